// Round 1
// baseline (4300.163 us; speedup 1.0000x reference)
//
#include <hip/hip_runtime.h>
#include <hip/hip_bf16.h>

#define T_ 32
#define B_ 16
#define I_ 512
#define H_ 512
#define OFF_ 441
#define NR_ 71           // I_ - OFF_
#define NC_ 2556         // NR_*(NR_+1)/2
#define G4_ (4*NC_)      // 10224
#define NS_ 8            // K-split for recurrent GEMM
#define KCH_ 320         // ceil(NC_/NS_)

__global__ void k_zero(float* __restrict__ p, int n) {
    int i = blockIdx.x * 256 + threadIdx.x;
    if (i < n) p[i] = 0.f;
}

// W (G4_ x NC_) row-major -> WT (NC_ x G4_) row-major, for l = 0,1
__global__ void k_transpose(const float* __restrict__ W0, const float* __restrict__ W1,
                            float* __restrict__ WT) {
    __shared__ float tile[32][33];
    const float* W = blockIdx.z ? W1 : W0;
    float* out = WT + (size_t)blockIdx.z * NC_ * G4_;
    int k0 = blockIdx.x * 32;   // col of W, row of WT
    int j0 = blockIdx.y * 32;   // row of W, col of WT
    int tx = threadIdx.x, ty = threadIdx.y;  // 32 x 8
    for (int r = ty; r < 32; r += 8) {
        int j = j0 + r, k = k0 + tx;
        tile[r][tx] = (j < G4_ && k < NC_) ? W[(size_t)j * NC_ + k] : 0.f;
    }
    __syncthreads();
    for (int r = ty; r < 32; r += 8) {
        int k = k0 + r, j = j0 + tx;
        if (k < NC_ && j < G4_) out[(size_t)k * G4_ + j] = tile[tx][r];
    }
}

// pre[l][t][b][jg] = sum_i X[t,b,i]*Wih_l[jg,i] + b_l[jg]
// C[m=512][n=10224] per l, tiled 64x64, K-tile 16, 4x4 per thread
__global__ __launch_bounds__(256) void k_gih(const float* __restrict__ X,
        const float* __restrict__ W0, const float* __restrict__ b0,
        const float* __restrict__ W1, const float* __restrict__ b1,
        float* __restrict__ pre) {
    const int l = blockIdx.z;
    const float* W = l ? W1 : W0;
    const float* bb = l ? b1 : b0;
    float* out = pre + (size_t)l * T_ * B_ * G4_;
    int m0 = blockIdx.x * 64;
    int n0 = blockIdx.y * 64;
    __shared__ float Xs[16][65];
    __shared__ float Ws[16][65];
    int tid = threadIdx.x;
    int tx = tid & 15, ty = tid >> 4;
    float acc[4][4] = {};
    for (int kt = 0; kt < I_; kt += 16) {
        #pragma unroll
        for (int r = 0; r < 4; ++r) {
            int m = m0 + (tid >> 4) + r * 16;
            int k = kt + (tid & 15);
            Xs[tid & 15][(tid >> 4) + r * 16] = X[(size_t)m * I_ + k];
        }
        #pragma unroll
        for (int r = 0; r < 4; ++r) {
            int n = n0 + (tid >> 4) + r * 16;
            int k = kt + (tid & 15);
            Ws[tid & 15][(tid >> 4) + r * 16] = (n < G4_) ? W[(size_t)n * I_ + k] : 0.f;
        }
        __syncthreads();
        #pragma unroll
        for (int kk = 0; kk < 16; ++kk) {
            float a[4], bv[4];
            #pragma unroll
            for (int p = 0; p < 4; ++p) a[p] = Xs[kk][ty * 4 + p];
            #pragma unroll
            for (int q = 0; q < 4; ++q) bv[q] = Ws[kk][tx * 4 + q];
            #pragma unroll
            for (int p = 0; p < 4; ++p)
                #pragma unroll
                for (int q = 0; q < 4; ++q) acc[p][q] += a[p] * bv[q];
        }
        __syncthreads();
    }
    #pragma unroll
    for (int p = 0; p < 4; ++p) {
        int m = m0 + ty * 4 + p;
        #pragma unroll
        for (int q = 0; q < 4; ++q) {
            int n = n0 + tx * 4 + q;
            if (n < G4_) out[(size_t)m * G4_ + n] = acc[p][q] + bb[n];
        }
    }
}

// Bt[k][h] = idct_hid[h][k] for k < 71
__global__ void k_bt(const float* __restrict__ Bh, float* __restrict__ Bt) {
    int idx = blockIdx.x * 256 + threadIdx.x;
    if (idx < NR_ * H_) {
        int k = idx / H_, h = idx - k * H_;
        Bt[idx] = Bh[(size_t)h * H_ + k];
    }
}

// partial[l][s][b][j] = sum_{k in chunk s} h_state[l][b][k] * WhhT[l][k][j]
// TRANS=1: Wmat is WT (NC_ x G4_). TRANS=0: Wmat is original (G4_ x NC_), strided fallback.
template <bool TRANS>
__global__ __launch_bounds__(256) void k_rec(const float* __restrict__ Wt0,
        const float* __restrict__ Wt1,
        const float* __restrict__ hst, float* __restrict__ part) {
    int j = blockIdx.x * 256 + threadIdx.x;
    int s = blockIdx.y, l = blockIdx.z;
    if (j >= G4_) return;
    const float* wmat = l ? Wt1 : Wt0;
    const float* h = hst + (size_t)l * B_ * NC_;
    int k0 = s * KCH_, k1 = (NC_ < k0 + KCH_) ? NC_ : (k0 + KCH_);
    float acc[B_] = {};
    #pragma unroll 4
    for (int k = k0; k < k1; ++k) {
        float w = TRANS ? wmat[(size_t)k * G4_ + j] : wmat[(size_t)j * NC_ + k];
        #pragma unroll
        for (int b = 0; b < B_; ++b) acc[b] += h[b * NC_ + k] * w;
    }
    float* po = part + ((size_t)(l * NS_ + s) * B_) * G4_ + j;
    #pragma unroll
    for (int b = 0; b < B_; ++b) po[(size_t)b * G4_] = acc[b];
}

__device__ __forceinline__ float sigf(float x) { return 1.f / (1.f + expf(-x)); }

// reduce K-split partials + pre, gate nonlinearities, update c,h; store h into hbuf[l][t][b][:]
__global__ void k_gate(const float* __restrict__ part, const float* __restrict__ pre,
                       float* __restrict__ cst, float* __restrict__ hst,
                       float* __restrict__ hbuf, int t) {
    int idx = blockIdx.x * 256 + threadIdx.x;
    if (idx >= 2 * B_ * NC_) return;
    int l = idx / (B_ * NC_);
    int r = idx - l * (B_ * NC_);
    int b = r / NC_;
    int jc = r - b * NC_;
    float g[4];
    #pragma unroll
    for (int q = 0; q < 4; ++q) {
        float s = pre[(((size_t)l * T_ + t) * B_ + b) * G4_ + q * NC_ + jc];
        for (int sp = 0; sp < NS_; ++sp)
            s += part[((size_t)(l * NS_ + sp) * B_ + b) * G4_ + q * NC_ + jc];
        g[q] = s;
    }
    float ci = cst[idx];
    float cn = sigf(g[1]) * ci + sigf(g[0]) * tanhf(g[2]);
    float hn = sigf(g[3]) * tanhf(cn);
    cst[idx] = cn;
    hst[idx] = hn;
    hbuf[(((size_t)l * T_ + t) * B_ + b) * NC_ + jc] = hn;
}

// yih[t,b,h] = sum_k Bt[k,h] * v[k], v[k] = sum_m coeff_ih[n]*scal[n]*u[70-k-m], u = idct_in^T x
__global__ __launch_bounds__(256) void k_yih(const float* __restrict__ x,
        const float* __restrict__ Ain, const float* __restrict__ Bt,
        const float* __restrict__ hbuf0, const float* __restrict__ scal,
        float* __restrict__ yih) {
    __shared__ float xl[I_];
    __shared__ float u[NR_];
    __shared__ float v[NR_];
    int tb = blockIdx.x;
    int tid = threadIdx.x;
    xl[tid] = x[(size_t)tb * I_ + tid];
    xl[tid + 256] = x[(size_t)tb * I_ + tid + 256];
    __syncthreads();
    if (tid < NR_) {
        float a = 0.f;
        for (int jj = 0; jj < I_; ++jj) a += Ain[(size_t)jj * I_ + tid] * xl[jj];
        u[tid] = a;
    }
    __syncthreads();
    if (tid < NR_) {
        int k = tid;
        int start = k * NR_ - (k * (k - 1)) / 2;
        int cnt = NR_ - k;
        const float* cf = hbuf0 + (size_t)tb * NC_;
        float a = 0.f;
        for (int m = 0; m < cnt; ++m) {
            int n = start + m;
            a += cf[n] * scal[n] * u[cnt - 1 - m];
        }
        v[k] = a;
    }
    __syncthreads();
    for (int h = tid; h < H_; h += 256) {
        float a = 0.f;
        #pragma unroll
        for (int k = 0; k < NR_; ++k) a += Bt[(size_t)k * H_ + h] * v[k];
        yih[(size_t)tb * H_ + h] = a;
    }
}

// sequential phase-2 over t; one block per batch b (independent recurrences)
__global__ __launch_bounds__(256) void k_seq(const float* __restrict__ yih,
        const float* __restrict__ Bt, const float* __restrict__ Ahid,
        const float* __restrict__ hbuf1, const float* __restrict__ scal,
        const float* __restrict__ bias, float* __restrict__ out) {
    __shared__ float hl[H_];
    __shared__ float u[NR_];
    __shared__ float v[NR_];
    int b = blockIdx.x, tid = threadIdx.x;
    hl[tid] = 0.f; hl[tid + 256] = 0.f;
    __syncthreads();
    for (int t = 0; t < T_; ++t) {
        if (tid < NR_) {
            float a = 0.f;
            for (int jj = 0; jj < H_; ++jj) a += Ahid[(size_t)jj * H_ + tid] * hl[jj];
            u[tid] = a;
        }
        __syncthreads();
        if (tid < NR_) {
            int k = tid;
            int start = k * NR_ - (k * (k - 1)) / 2;
            int cnt = NR_ - k;
            const float* cf = hbuf1 + ((size_t)t * B_ + b) * NC_;
            float a = 0.f;
            for (int m = 0; m < cnt; ++m) {
                int n = start + m;
                a += cf[n] * scal[n] * u[cnt - 1 - m];
            }
            v[k] = a;
        }
        __syncthreads();
        float hv[2];
        #pragma unroll
        for (int hh = 0; hh < 2; ++hh) {
            int h = tid + hh * 256;
            float a = 0.f;
            #pragma unroll
            for (int k = 0; k < NR_; ++k) a += Bt[(size_t)k * H_ + h] * v[k];
            hv[hh] = tanhf(yih[((size_t)t * B_ + b) * H_ + h] + a + bias[h]);
            out[((size_t)t * B_ + b) * H_ + h] = hv[hh];
        }
        __syncthreads();
        hl[tid] = hv[0]; hl[tid + 256] = hv[1];
        __syncthreads();
    }
}

extern "C" void kernel_launch(void* const* d_in, const int* in_sizes, int n_in,
                              void* d_out, int out_size, void* d_ws, size_t ws_size,
                              hipStream_t stream) {
    const float* x        = (const float*)d_in[0];
    const float* wih_ih   = (const float*)d_in[1];
    const float* wih_hh   = (const float*)d_in[2];
    const float* wih_b    = (const float*)d_in[3];
    const float* whh_ih   = (const float*)d_in[4];
    const float* whh_hh   = (const float*)d_in[5];
    const float* whh_b    = (const float*)d_in[6];
    const float* scal_ih  = (const float*)d_in[7];
    const float* scal_hh  = (const float*)d_in[8];
    const float* bias     = (const float*)d_in[9];
    const float* idct_in  = (const float*)d_in[10];
    const float* idct_hid = (const float*)d_in[11];
    float* out = (float*)d_out;

    char* ws = (char*)d_ws;
    size_t off = 0;
    auto alloc = [&](size_t bytes) -> float* {
        float* p = (float*)(ws + off);
        off += (bytes + 255) & ~(size_t)255;
        return p;
    };
    const size_t wt_bytes   = (size_t)2 * NC_ * G4_ * sizeof(float);
    const size_t rest_bytes = ((size_t)2 * T_ * B_ * G4_   // pre
                             + (size_t)2 * NS_ * B_ * G4_  // part
                             + (size_t)2 * T_ * B_ * NC_   // hbuf
                             + (size_t)4 * B_ * NC_        // hst + cst
                             + (size_t)T_ * B_ * H_        // yih
                             + (size_t)NR_ * H_) * sizeof(float) + 8192;
    bool useWT = (ws_size >= wt_bytes + rest_bytes);

    float* WT   = useWT ? alloc(wt_bytes) : nullptr;
    float* pre  = alloc((size_t)2 * T_ * B_ * G4_ * sizeof(float));
    float* part = alloc((size_t)2 * NS_ * B_ * G4_ * sizeof(float));
    float* hbuf = alloc((size_t)2 * T_ * B_ * NC_ * sizeof(float));
    float* hst  = alloc((size_t)2 * B_ * NC_ * sizeof(float));
    float* cst  = alloc((size_t)2 * B_ * NC_ * sizeof(float));
    float* yih  = alloc((size_t)T_ * B_ * H_ * sizeof(float));
    float* Bt   = alloc((size_t)NR_ * H_ * sizeof(float));

    {
        int n = 2 * B_ * NC_;
        hipLaunchKernelGGL(k_zero, dim3((n + 255) / 256), dim3(256), 0, stream, hst, n);
        hipLaunchKernelGGL(k_zero, dim3((n + 255) / 256), dim3(256), 0, stream, cst, n);
    }
    if (useWT) {
        hipLaunchKernelGGL(k_transpose, dim3(80, 320, 2), dim3(32, 8), 0, stream,
                           wih_hh, whh_hh, WT);
    }
    hipLaunchKernelGGL(k_gih, dim3(8, 160, 2), dim3(256), 0, stream,
                       x, wih_ih, wih_b, whh_ih, whh_b, pre);
    hipLaunchKernelGGL(k_bt, dim3((NR_ * H_ + 255) / 256), dim3(256), 0, stream,
                       idct_hid, Bt);

    for (int t = 0; t < T_; ++t) {
        if (useWT) {
            hipLaunchKernelGGL((k_rec<true>), dim3(40, NS_, 2), dim3(256), 0, stream,
                               WT, WT + (size_t)NC_ * G4_, hst, part);
        } else {
            hipLaunchKernelGGL((k_rec<false>), dim3(40, NS_, 2), dim3(256), 0, stream,
                               wih_hh, whh_hh, hst, part);
        }
        hipLaunchKernelGGL(k_gate, dim3((2 * B_ * NC_ + 255) / 256), dim3(256), 0, stream,
                           part, pre, cst, hst, hbuf, t);
    }

    hipLaunchKernelGGL(k_yih, dim3(T_ * B_), dim3(256), 0, stream,
                       x, idct_in, Bt, hbuf, scal_ih, yih);
    hipLaunchKernelGGL(k_seq, dim3(B_), dim3(256), 0, stream,
                       yih, Bt, idct_hid, hbuf + (size_t)T_ * B_ * NC_, scal_hh, bias, out);
}

// Round 2
// 3238.063 us; speedup vs baseline: 1.3280x; 1.3280x over previous
//
#include <hip/hip_runtime.h>
#include <hip/hip_bf16.h>

#define T_ 32
#define B_ 16
#define I_ 512
#define H_ 512
#define OFF_ 441
#define NR_ 71           // I_ - OFF_
#define NC_ 2556         // NR_*(NR_+1)/2
#define G4_ (4*NC_)      // 10224
#define NS_ 8            // K-split for recurrent GEMM
#define KCH_ 320         // ceil(NC_/NS_)

__global__ void k_zero(float* __restrict__ p, int n) {
    int i = blockIdx.x * 256 + threadIdx.x;
    if (i < n) p[i] = 0.f;
}

// W (G4_ x NC_) fp32 row-major -> WT (NC_ x G4_) bf16 row-major, for l = 0,1
__global__ void k_transpose_bf16(const float* __restrict__ W0, const float* __restrict__ W1,
                                 __hip_bfloat16* __restrict__ WT) {
    __shared__ float tile[32][33];
    const float* W = blockIdx.z ? W1 : W0;
    __hip_bfloat16* out = WT + (size_t)blockIdx.z * NC_ * G4_;
    int k0 = blockIdx.x * 32;   // col of W, row of WT
    int j0 = blockIdx.y * 32;   // row of W, col of WT
    int tx = threadIdx.x, ty = threadIdx.y;  // 32 x 8
    for (int r = ty; r < 32; r += 8) {
        int j = j0 + r, k = k0 + tx;
        tile[r][tx] = (j < G4_ && k < NC_) ? W[(size_t)j * NC_ + k] : 0.f;
    }
    __syncthreads();
    for (int r = ty; r < 32; r += 8) {
        int k = k0 + r, j = j0 + tx;
        if (k < NC_ && j < G4_) out[(size_t)k * G4_ + j] = __float2bfloat16(tile[tx][r]);
    }
}

// pre[l][t][b][jg] = sum_i X[t,b,i]*Wih_l[jg,i] + b_l[jg]
__global__ __launch_bounds__(256) void k_gih(const float* __restrict__ X,
        const float* __restrict__ W0, const float* __restrict__ b0,
        const float* __restrict__ W1, const float* __restrict__ b1,
        float* __restrict__ pre) {
    const int l = blockIdx.z;
    const float* W = l ? W1 : W0;
    const float* bb = l ? b1 : b0;
    float* out = pre + (size_t)l * T_ * B_ * G4_;
    int m0 = blockIdx.x * 64;
    int n0 = blockIdx.y * 64;
    __shared__ float Xs[16][65];
    __shared__ float Ws[16][65];
    int tid = threadIdx.x;
    int tx = tid & 15, ty = tid >> 4;
    float acc[4][4] = {};
    for (int kt = 0; kt < I_; kt += 16) {
        #pragma unroll
        for (int r = 0; r < 4; ++r) {
            int m = m0 + (tid >> 4) + r * 16;
            int k = kt + (tid & 15);
            Xs[tid & 15][(tid >> 4) + r * 16] = X[(size_t)m * I_ + k];
        }
        #pragma unroll
        for (int r = 0; r < 4; ++r) {
            int n = n0 + (tid >> 4) + r * 16;
            int k = kt + (tid & 15);
            Ws[tid & 15][(tid >> 4) + r * 16] = (n < G4_) ? W[(size_t)n * I_ + k] : 0.f;
        }
        __syncthreads();
        #pragma unroll
        for (int kk = 0; kk < 16; ++kk) {
            float a[4], bv[4];
            #pragma unroll
            for (int p = 0; p < 4; ++p) a[p] = Xs[kk][ty * 4 + p];
            #pragma unroll
            for (int q = 0; q < 4; ++q) bv[q] = Ws[kk][tx * 4 + q];
            #pragma unroll
            for (int p = 0; p < 4; ++p)
                #pragma unroll
                for (int q = 0; q < 4; ++q) acc[p][q] += a[p] * bv[q];
        }
        __syncthreads();
    }
    #pragma unroll
    for (int p = 0; p < 4; ++p) {
        int m = m0 + ty * 4 + p;
        #pragma unroll
        for (int q = 0; q < 4; ++q) {
            int n = n0 + tx * 4 + q;
            if (n < G4_) out[(size_t)m * G4_ + n] = acc[p][q] + bb[n];
        }
    }
}

// Bt[k][h] = idct_hid[h][k] for k < 71
__global__ void k_bt(const float* __restrict__ Bh, float* __restrict__ Bt) {
    int idx = blockIdx.x * 256 + threadIdx.x;
    if (idx < NR_ * H_) {
        int k = idx / H_, h = idx - k * H_;
        Bt[idx] = Bh[(size_t)h * H_ + k];
    }
}

// bf16 recurrent GEMM: part[l][s][b][j] = sum_{k in chunk s} h[l][b][k] * WT[l][k][j]
__global__ __launch_bounds__(256) void k_rec2(const ushort* __restrict__ WT,
        const float* __restrict__ hst, float* __restrict__ part) {
    const int tid = threadIdx.x;
    const int s = blockIdx.y, l = blockIdx.z;
    const int j0 = (blockIdx.x * 256 + tid) * 2;
    const ushort* w = WT + (size_t)l * NC_ * G4_;
    const float* h = hst + (size_t)l * B_ * NC_;
    __shared__ float hl[KCH_][20];
    const int k0 = s * KCH_;
    const int kcnt = (NC_ - k0 < KCH_) ? (NC_ - k0) : KCH_;
    #pragma unroll
    for (int b = 0; b < B_; ++b)
        for (int k = tid; k < kcnt; k += 256)
            hl[k][b] = h[(size_t)b * NC_ + k0 + k];
    __syncthreads();
    float acc0[B_] = {}, acc1[B_] = {};
    if (j0 < G4_) {
        const ushort* wp = w + (size_t)k0 * G4_ + j0;
        #pragma unroll 2
        for (int kk = 0; kk < kcnt; ++kk) {
            uint pair = *(const uint*)wp;
            wp += G4_;
            float w0 = __uint_as_float(pair << 16);
            float w1 = __uint_as_float(pair & 0xffff0000u);
            float hv[16];
            const float4* hr = (const float4*)&hl[kk][0];
            *(float4*)&hv[0]  = hr[0];
            *(float4*)&hv[4]  = hr[1];
            *(float4*)&hv[8]  = hr[2];
            *(float4*)&hv[12] = hr[3];
            #pragma unroll
            for (int b = 0; b < B_; ++b) {
                acc0[b] += hv[b] * w0;
                acc1[b] += hv[b] * w1;
            }
        }
        float* po = part + ((size_t)(l * NS_ + s) * B_) * G4_;
        #pragma unroll
        for (int b = 0; b < B_; ++b) {
            float2 st; st.x = acc0[b]; st.y = acc1[b];
            *(float2*)(po + (size_t)b * G4_ + j0) = st;
        }
    }
}

// fp32 fallback (strided) if workspace too small for WT
template <bool TRANS>
__global__ __launch_bounds__(256) void k_rec(const float* __restrict__ Wt0,
        const float* __restrict__ Wt1,
        const float* __restrict__ hst, float* __restrict__ part) {
    int j = blockIdx.x * 256 + threadIdx.x;
    int s = blockIdx.y, l = blockIdx.z;
    if (j >= G4_) return;
    const float* wmat = l ? Wt1 : Wt0;
    const float* h = hst + (size_t)l * B_ * NC_;
    int k0 = s * KCH_, k1 = (NC_ < k0 + KCH_) ? NC_ : (k0 + KCH_);
    float acc[B_] = {};
    #pragma unroll 4
    for (int k = k0; k < k1; ++k) {
        float w = TRANS ? wmat[(size_t)k * G4_ + j] : wmat[(size_t)j * NC_ + k];
        #pragma unroll
        for (int b = 0; b < B_; ++b) acc[b] += h[b * NC_ + k] * w;
    }
    float* po = part + ((size_t)(l * NS_ + s) * B_) * G4_ + j;
    #pragma unroll
    for (int b = 0; b < B_; ++b) po[(size_t)b * G4_] = acc[b];
}

__device__ __forceinline__ float sigf(float x) { return 1.f / (1.f + expf(-x)); }

// reduce K-split partials + pre, gates, update c,h; store scaled h into hbuf
__global__ void k_gate(const float* __restrict__ part, const float* __restrict__ pre,
                       const float* __restrict__ scal_ih, const float* __restrict__ scal_hh,
                       float* __restrict__ cst, float* __restrict__ hst,
                       float* __restrict__ hbuf, int t) {
    int idx = blockIdx.x * 256 + threadIdx.x;
    if (idx >= 2 * B_ * NC_) return;
    int l = idx / (B_ * NC_);
    int r = idx - l * (B_ * NC_);
    int b = r / NC_;
    int jc = r - b * NC_;
    float g[4];
    #pragma unroll
    for (int q = 0; q < 4; ++q) {
        float s = pre[(((size_t)l * T_ + t) * B_ + b) * G4_ + q * NC_ + jc];
        for (int sp = 0; sp < NS_; ++sp)
            s += part[((size_t)(l * NS_ + sp) * B_ + b) * G4_ + q * NC_ + jc];
        g[q] = s;
    }
    float ci = cst[idx];
    float cn = sigf(g[1]) * ci + sigf(g[0]) * tanhf(g[2]);
    float hn = sigf(g[3]) * tanhf(cn);
    cst[idx] = cn;
    hst[idx] = hn;
    float sc = (l ? scal_hh : scal_ih)[jc];
    hbuf[(((size_t)l * T_ + t) * B_ + b) * NC_ + jc] = hn * sc;
}

// yih[t,b,h] = sum_k Bt[k,h] * v[k]; coeffs pre-scaled in hbuf
__global__ __launch_bounds__(256) void k_yih(const float* __restrict__ x,
        const float* __restrict__ Ain, const float* __restrict__ Bt,
        const float* __restrict__ hbuf0, float* __restrict__ yih) {
    __shared__ float xl[I_];
    __shared__ float u[NR_];
    __shared__ float v[NR_];
    int tb = blockIdx.x;
    int tid = threadIdx.x;
    xl[tid] = x[(size_t)tb * I_ + tid];
    xl[tid + 256] = x[(size_t)tb * I_ + tid + 256];
    __syncthreads();
    if (tid < NR_) {
        float a = 0.f;
        for (int jj = 0; jj < I_; ++jj) a += Ain[(size_t)jj * I_ + tid] * xl[jj];
        u[tid] = a;
    }
    __syncthreads();
    if (tid < NR_) {
        int k = tid;
        int start = k * NR_ - (k * (k - 1)) / 2;
        int cnt = NR_ - k;
        const float* cf = hbuf0 + (size_t)tb * NC_;
        float a = 0.f;
        for (int m = 0; m < cnt; ++m) a += cf[start + m] * u[cnt - 1 - m];
        v[k] = a;
    }
    __syncthreads();
    for (int h = tid; h < H_; h += 256) {
        float a = 0.f;
        #pragma unroll
        for (int k = 0; k < NR_; ++k) a += Bt[(size_t)k * H_ + h] * v[k];
        yih[(size_t)tb * H_ + h] = a;
    }
}

// sequential phase-2 over t; one block per batch; 8-lane-group parallel reductions
__global__ __launch_bounds__(576) void k_seq(const float* __restrict__ yih,
        const float* __restrict__ Bt, const float* __restrict__ cf_all,
        const float* __restrict__ bias, float* __restrict__ out) {
    __shared__ float hl[H_];
    __shared__ float u[NR_ + 1];
    __shared__ float v[NR_ + 1];
    const int b = blockIdx.x, tid = threadIdx.x;
    const int g = tid >> 3, lane = tid & 7;
    for (int i = tid; i < H_; i += 576) hl[i] = 0.f;
    __syncthreads();
    for (int t = 0; t < T_; ++t) {
        // u[g] = sum_j Bt[g][j] * h[j]
        if (g < NR_) {
            float a = 0.f;
            const float* bp = Bt + (size_t)g * H_;
            for (int j = lane; j < H_; j += 8) a += bp[j] * hl[j];
            a += __shfl_xor(a, 1);
            a += __shfl_xor(a, 2);
            a += __shfl_xor(a, 4);
            if (lane == 0) u[g] = a;
        }
        __syncthreads();
        // v[g] = triangular combine with pre-scaled coeffs
        if (g < NR_) {
            int start = g * NR_ - (g * (g - 1)) / 2;
            int cnt = NR_ - g;
            const float* cf = cf_all + ((size_t)t * B_ + b) * NC_ + start;
            float a = 0.f;
            for (int m = lane; m < cnt; m += 8) a += cf[m] * u[cnt - 1 - m];
            a += __shfl_xor(a, 1);
            a += __shfl_xor(a, 2);
            a += __shfl_xor(a, 4);
            if (lane == 0) v[g] = a;
        }
        __syncthreads();
        float hv = 0.f;
        if (tid < H_) {
            float a0 = 0.f, a1 = 0.f;
            #pragma unroll
            for (int k = 0; k < NR_ - 1; k += 2) {
                a0 += Bt[(size_t)k * H_ + tid] * v[k];
                a1 += Bt[(size_t)(k + 1) * H_ + tid] * v[k + 1];
            }
            a0 += Bt[(size_t)(NR_ - 1) * H_ + tid] * v[NR_ - 1];
            hv = tanhf(yih[((size_t)t * B_ + b) * H_ + tid] + a0 + a1 + bias[tid]);
            out[((size_t)t * B_ + b) * H_ + tid] = hv;
        }
        __syncthreads();
        if (tid < H_) hl[tid] = hv;
        __syncthreads();
    }
}

extern "C" void kernel_launch(void* const* d_in, const int* in_sizes, int n_in,
                              void* d_out, int out_size, void* d_ws, size_t ws_size,
                              hipStream_t stream) {
    const float* x        = (const float*)d_in[0];
    const float* wih_ih   = (const float*)d_in[1];
    const float* wih_hh   = (const float*)d_in[2];
    const float* wih_b    = (const float*)d_in[3];
    const float* whh_ih   = (const float*)d_in[4];
    const float* whh_hh   = (const float*)d_in[5];
    const float* whh_b    = (const float*)d_in[6];
    const float* scal_ih  = (const float*)d_in[7];
    const float* scal_hh  = (const float*)d_in[8];
    const float* bias     = (const float*)d_in[9];
    const float* idct_in  = (const float*)d_in[10];
    const float* idct_hid = (const float*)d_in[11];
    float* out = (float*)d_out;

    char* ws = (char*)d_ws;
    size_t off = 0;
    auto alloc = [&](size_t bytes) -> void* {
        void* p = (void*)(ws + off);
        off += (bytes + 255) & ~(size_t)255;
        return p;
    };
    const size_t wt_bytes   = (size_t)2 * NC_ * G4_ * sizeof(ushort);
    const size_t rest_bytes = ((size_t)2 * T_ * B_ * G4_
                             + (size_t)2 * NS_ * B_ * G4_
                             + (size_t)2 * T_ * B_ * NC_
                             + (size_t)4 * B_ * NC_
                             + (size_t)T_ * B_ * H_
                             + (size_t)NR_ * H_) * sizeof(float) + 8192;
    bool useWT = (ws_size >= wt_bytes + rest_bytes);

    ushort* WT  = useWT ? (ushort*)alloc(wt_bytes) : nullptr;
    float* pre  = (float*)alloc((size_t)2 * T_ * B_ * G4_ * sizeof(float));
    float* part = (float*)alloc((size_t)2 * NS_ * B_ * G4_ * sizeof(float));
    float* hbuf = (float*)alloc((size_t)2 * T_ * B_ * NC_ * sizeof(float));
    float* hst  = (float*)alloc((size_t)2 * B_ * NC_ * sizeof(float));
    float* cst  = (float*)alloc((size_t)2 * B_ * NC_ * sizeof(float));
    float* yih  = (float*)alloc((size_t)T_ * B_ * H_ * sizeof(float));
    float* Bt   = (float*)alloc((size_t)NR_ * H_ * sizeof(float));

    {
        int n = 2 * B_ * NC_;
        hipLaunchKernelGGL(k_zero, dim3((n + 255) / 256), dim3(256), 0, stream, hst, n);
        hipLaunchKernelGGL(k_zero, dim3((n + 255) / 256), dim3(256), 0, stream, cst, n);
    }
    if (useWT) {
        hipLaunchKernelGGL(k_transpose_bf16, dim3(80, 320, 2), dim3(32, 8), 0, stream,
                           wih_hh, whh_hh, (__hip_bfloat16*)WT);
    }
    hipLaunchKernelGGL(k_gih, dim3(8, 160, 2), dim3(256), 0, stream,
                       x, wih_ih, wih_b, whh_ih, whh_b, pre);
    hipLaunchKernelGGL(k_bt, dim3((NR_ * H_ + 255) / 256), dim3(256), 0, stream,
                       idct_hid, Bt);

    for (int t = 0; t < T_; ++t) {
        if (useWT) {
            hipLaunchKernelGGL(k_rec2, dim3(20, NS_, 2), dim3(256), 0, stream,
                               WT, hst, part);
        } else {
            hipLaunchKernelGGL((k_rec<false>), dim3(40, NS_, 2), dim3(256), 0, stream,
                               wih_hh, whh_hh, hst, part);
        }
        hipLaunchKernelGGL(k_gate, dim3((2 * B_ * NC_ + 255) / 256), dim3(256), 0, stream,
                           part, pre, scal_ih, scal_hh, cst, hst, hbuf, t);
    }

    hipLaunchKernelGGL(k_yih, dim3(T_ * B_), dim3(256), 0, stream,
                       x, idct_in, Bt, hbuf, yih);
    hipLaunchKernelGGL(k_seq, dim3(B_), dim3(576), 0, stream,
                       yih, Bt, hbuf + (size_t)T_ * B_ * NC_, bias, out);
}

// Round 3
// 2122.740 us; speedup vs baseline: 2.0258x; 1.5254x over previous
//
#include <hip/hip_runtime.h>
#include <hip/hip_bf16.h>

#define T_ 32
#define B_ 16
#define I_ 512
#define H_ 512
#define OFF_ 441
#define NR_ 71           // I_ - OFF_
#define NC_ 2556         // NR_*(NR_+1)/2
#define G4_ (4*NC_)      // 10224
#define NS_ 8            // K-split for recurrent GEMM
#define KCH_ 320         // ceil(NC_/NS_)

__global__ void k_zero(float* __restrict__ p, int n) {
    int i = blockIdx.x * 256 + threadIdx.x;
    if (i < n) p[i] = 0.f;
}

// W (G4_ x NC_) fp32 row-major -> WT (NC_ x G4_) bf16 row-major, for l = 0,1
__global__ void k_transpose_bf16(const float* __restrict__ W0, const float* __restrict__ W1,
                                 __hip_bfloat16* __restrict__ WT) {
    __shared__ float tile[32][33];
    const float* W = blockIdx.z ? W1 : W0;
    __hip_bfloat16* out = WT + (size_t)blockIdx.z * NC_ * G4_;
    int k0 = blockIdx.x * 32;   // col of W, row of WT
    int j0 = blockIdx.y * 32;   // row of W, col of WT
    int tx = threadIdx.x, ty = threadIdx.y;  // 32 x 8
    for (int r = ty; r < 32; r += 8) {
        int j = j0 + r, k = k0 + tx;
        tile[r][tx] = (j < G4_ && k < NC_) ? W[(size_t)j * NC_ + k] : 0.f;
    }
    __syncthreads();
    for (int r = ty; r < 32; r += 8) {
        int k = k0 + r, j = j0 + tx;
        if (k < NC_ && j < G4_) out[(size_t)k * G4_ + j] = __float2bfloat16(tile[tx][r]);
    }
}

// pre[l][t][b][jg] = sum_i X[t,b,i]*Wih_l[jg,i] + b_l[jg]
// 128x64 tile, BK=16, 8x4 per thread, 256 threads
__global__ __launch_bounds__(256) void k_gih(const float* __restrict__ X,
        const float* __restrict__ W0, const float* __restrict__ b0,
        const float* __restrict__ W1, const float* __restrict__ b1,
        float* __restrict__ pre) {
    const int l = blockIdx.z;
    const float* W = l ? W1 : W0;
    const float* bb = l ? b1 : b0;
    float* out = pre + (size_t)l * T_ * B_ * G4_;
    const int m0 = blockIdx.x * 128;
    const int n0 = blockIdx.y * 64;
    __shared__ float Xs[16][132];
    __shared__ float Ws[16][68];
    const int tid = threadIdx.x;
    const int tx = tid & 15, ty = tid >> 4;
    float acc[8][4] = {};
    for (int kt = 0; kt < I_; kt += 16) {
        // stage X: 128 rows x 16 k
        #pragma unroll
        for (int i = 0; i < 2; ++i) {
            int idx = tid + i * 256;           // 0..511 float4 slots
            int kq = idx >> 7, m = idx & 127;
            float4 xv = *(const float4*)&X[(size_t)(m0 + m) * I_ + kt + kq * 4];
            Xs[kq * 4 + 0][m] = xv.x;
            Xs[kq * 4 + 1][m] = xv.y;
            Xs[kq * 4 + 2][m] = xv.z;
            Xs[kq * 4 + 3][m] = xv.w;
        }
        // stage W: 64 rows x 16 k
        {
            int n = tid >> 2, kq = tid & 3;
            float4 wv = make_float4(0.f, 0.f, 0.f, 0.f);
            if (n0 + n < G4_)
                wv = *(const float4*)&W[(size_t)(n0 + n) * I_ + kt + kq * 4];
            Ws[kq * 4 + 0][n] = wv.x;
            Ws[kq * 4 + 1][n] = wv.y;
            Ws[kq * 4 + 2][n] = wv.z;
            Ws[kq * 4 + 3][n] = wv.w;
        }
        __syncthreads();
        #pragma unroll
        for (int kk = 0; kk < 16; ++kk) {
            float a[8], bv[4];
            #pragma unroll
            for (int p = 0; p < 8; ++p) a[p] = Xs[kk][ty * 8 + p];
            #pragma unroll
            for (int q = 0; q < 4; ++q) bv[q] = Ws[kk][tx * 4 + q];
            #pragma unroll
            for (int p = 0; p < 8; ++p)
                #pragma unroll
                for (int q = 0; q < 4; ++q) acc[p][q] += a[p] * bv[q];
        }
        __syncthreads();
    }
    #pragma unroll
    for (int p = 0; p < 8; ++p) {
        int m = m0 + ty * 8 + p;
        #pragma unroll
        for (int q = 0; q < 4; ++q) {
            int n = n0 + tx * 4 + q;
            if (n < G4_) out[(size_t)m * G4_ + n] = acc[p][q] + bb[n];
        }
    }
}

// Bt[k][h] = idct_hid[h][k] for k < 71
__global__ void k_bt(const float* __restrict__ Bh, float* __restrict__ Bt) {
    int idx = blockIdx.x * 256 + threadIdx.x;
    if (idx < NR_ * H_) {
        int k = idx / H_, h = idx - k * H_;
        Bt[idx] = Bh[(size_t)h * H_ + k];
    }
}

// bf16 recurrent GEMM, double-buffered k-unroll-4:
// part[l][s][b][j] = sum_{k in chunk s} h[l][b][k] * WT[l][k][j]
__global__ __launch_bounds__(256) void k_rec2(const ushort* __restrict__ WT,
        const float* __restrict__ hst, float* __restrict__ part) {
    const int tid = threadIdx.x;
    const int s = blockIdx.y, l = blockIdx.z;
    const int j0 = (blockIdx.x * 256 + tid) * 2;
    const ushort* w = WT + (size_t)l * NC_ * G4_;
    const float* h = hst + (size_t)l * B_ * NC_;
    __shared__ float hl[KCH_][20];
    const int k0 = s * KCH_;
    const int kcnt = (NC_ - k0 < KCH_) ? (NC_ - k0) : KCH_;   // 320 or 316, %4==0
    #pragma unroll
    for (int b = 0; b < B_; ++b)
        for (int k = tid; k < kcnt; k += 256)
            hl[k][b] = h[(size_t)b * NC_ + k0 + k];
    __syncthreads();
    float acc0[B_] = {}, acc1[B_] = {};
    if (j0 < G4_) {
        const uint* wp = (const uint*)(w + (size_t)k0 * G4_ + j0);
        const size_t st = G4_ / 2;   // row stride in uints
        const int nIter = kcnt >> 2;
        uint c0 = wp[0], c1 = wp[st], c2 = wp[2 * st], c3 = wp[3 * st];
        wp += 4 * st;
        for (int it = 0; it < nIter - 1; ++it) {
            uint n0 = wp[0], n1 = wp[st], n2 = wp[2 * st], n3 = wp[3 * st];
            wp += 4 * st;
            int kb = it * 4;
            uint cc[4] = {c0, c1, c2, c3};
            #pragma unroll
            for (int i = 0; i < 4; ++i) {
                float w0 = __uint_as_float(cc[i] << 16);
                float w1 = __uint_as_float(cc[i] & 0xffff0000u);
                const float* hr = hl[kb + i];
                #pragma unroll
                for (int b = 0; b < B_; ++b) {
                    acc0[b] += hr[b] * w0;
                    acc1[b] += hr[b] * w1;
                }
            }
            c0 = n0; c1 = n1; c2 = n2; c3 = n3;
        }
        {
            int kb = (nIter - 1) * 4;
            uint cc[4] = {c0, c1, c2, c3};
            #pragma unroll
            for (int i = 0; i < 4; ++i) {
                float w0 = __uint_as_float(cc[i] << 16);
                float w1 = __uint_as_float(cc[i] & 0xffff0000u);
                const float* hr = hl[kb + i];
                #pragma unroll
                for (int b = 0; b < B_; ++b) {
                    acc0[b] += hr[b] * w0;
                    acc1[b] += hr[b] * w1;
                }
            }
        }
        float* po = part + ((size_t)(l * NS_ + s) * B_) * G4_;
        #pragma unroll
        for (int b = 0; b < B_; ++b) {
            float2 stv; stv.x = acc0[b]; stv.y = acc1[b];
            *(float2*)(po + (size_t)b * G4_ + j0) = stv;
        }
    }
}

// fp32 fallback (strided) if workspace too small for WT
template <bool TRANS>
__global__ __launch_bounds__(256) void k_rec(const float* __restrict__ Wt0,
        const float* __restrict__ Wt1,
        const float* __restrict__ hst, float* __restrict__ part) {
    int j = blockIdx.x * 256 + threadIdx.x;
    int s = blockIdx.y, l = blockIdx.z;
    if (j >= G4_) return;
    const float* wmat = l ? Wt1 : Wt0;
    const float* h = hst + (size_t)l * B_ * NC_;
    int k0 = s * KCH_, k1 = (NC_ < k0 + KCH_) ? NC_ : (k0 + KCH_);
    float acc[B_] = {};
    #pragma unroll 4
    for (int k = k0; k < k1; ++k) {
        float w = TRANS ? wmat[(size_t)k * G4_ + j] : wmat[(size_t)j * NC_ + k];
        #pragma unroll
        for (int b = 0; b < B_; ++b) acc[b] += h[b * NC_ + k] * w;
    }
    float* po = part + ((size_t)(l * NS_ + s) * B_) * G4_ + j;
    #pragma unroll
    for (int b = 0; b < B_; ++b) po[(size_t)b * G4_] = acc[b];
}

__device__ __forceinline__ float sigf(float x) { return 1.f / (1.f + expf(-x)); }

// reduce K-split partials + pre, gates, update c,h; store scaled h into hbuf
__global__ void k_gate(const float* __restrict__ part, const float* __restrict__ pre,
                       const float* __restrict__ scal_ih, const float* __restrict__ scal_hh,
                       float* __restrict__ cst, float* __restrict__ hst,
                       float* __restrict__ hbuf, int t) {
    int idx = blockIdx.x * 256 + threadIdx.x;
    if (idx >= 2 * B_ * NC_) return;
    int l = idx / (B_ * NC_);
    int r = idx - l * (B_ * NC_);
    int b = r / NC_;
    int jc = r - b * NC_;
    float g[4];
    #pragma unroll
    for (int q = 0; q < 4; ++q) {
        float s = pre[(((size_t)l * T_ + t) * B_ + b) * G4_ + q * NC_ + jc];
        #pragma unroll
        for (int sp = 0; sp < NS_; ++sp)
            s += part[((size_t)(l * NS_ + sp) * B_ + b) * G4_ + q * NC_ + jc];
        g[q] = s;
    }
    float ci = cst[idx];
    float cn = sigf(g[1]) * ci + sigf(g[0]) * tanhf(g[2]);
    float hn = sigf(g[3]) * tanhf(cn);
    cst[idx] = cn;
    hst[idx] = hn;
    float sc = (l ? scal_hh : scal_ih)[jc];
    hbuf[(((size_t)l * T_ + t) * B_ + b) * NC_ + jc] = hn * sc;
}

// yih[t,b,h] = sum_k Bt[k,h] * v[k]; coeffs pre-scaled in hbuf
__global__ __launch_bounds__(256) void k_yih(const float* __restrict__ x,
        const float* __restrict__ Ain, const float* __restrict__ Bt,
        const float* __restrict__ hbuf0, float* __restrict__ yih) {
    __shared__ float xl[I_];
    __shared__ float u[NR_];
    __shared__ float v[NR_];
    int tb = blockIdx.x;
    int tid = threadIdx.x;
    xl[tid] = x[(size_t)tb * I_ + tid];
    xl[tid + 256] = x[(size_t)tb * I_ + tid + 256];
    __syncthreads();
    if (tid < NR_) {
        float a = 0.f;
        for (int jj = 0; jj < I_; ++jj) a += Ain[(size_t)jj * I_ + tid] * xl[jj];
        u[tid] = a;
    }
    __syncthreads();
    if (tid < NR_) {
        int k = tid;
        int start = k * NR_ - (k * (k - 1)) / 2;
        int cnt = NR_ - k;
        const float* cf = hbuf0 + (size_t)tb * NC_;
        float a = 0.f;
        for (int m = 0; m < cnt; ++m) a += cf[start + m] * u[cnt - 1 - m];
        v[k] = a;
    }
    __syncthreads();
    for (int h = tid; h < H_; h += 256) {
        float a = 0.f;
        #pragma unroll
        for (int k = 0; k < NR_; ++k) a += Bt[(size_t)k * H_ + h] * v[k];
        yih[(size_t)tb * H_ + h] = a;
    }
}

// sequential phase-2; one block per batch; full Bt staged in LDS (fp32, padded)
#define BTP_ 516
__global__ __launch_bounds__(576) void k_seq(const float* __restrict__ yih,
        const float* __restrict__ Bt, const float* __restrict__ cf_all,
        const float* __restrict__ bias, float* __restrict__ out) {
    __shared__ float bt[NR_][BTP_];   // 71*516*4 = 146.5 KB
    __shared__ float hl[H_];
    __shared__ float u[NR_ + 1];
    __shared__ float v[NR_ + 1];
    const int b = blockIdx.x, tid = threadIdx.x;
    for (int i = tid; i < NR_ * H_; i += 576) {
        int k = i >> 9, hh = i & 511;
        bt[k][hh] = Bt[i];
    }
    for (int i = tid; i < H_; i += 576) hl[i] = 0.f;
    const float bv = (tid < H_) ? bias[tid] : 0.f;
    const int g = tid >> 3, lane = tid & 7;
    int start = 0, cnt = 0;
    if (g < NR_) { start = g * NR_ - (g * (g - 1)) / 2; cnt = NR_ - g; }
    __syncthreads();
    for (int t = 0; t < T_; ++t) {
        // prefetch cf into regs (masked; hidden under u-phase)
        float cfv[9];
        if (g < NR_) {
            const float* cf = cf_all + ((size_t)t * B_ + b) * NC_ + start;
            #pragma unroll
            for (int mi = 0; mi < 9; ++mi) {
                int m = mi * 8 + lane;
                int mc = m < cnt ? m : (cnt - 1);
                cfv[mi] = cf[mc];
            }
        }
        // u[g] = sum_j bt[g][j] * h[j]   (all LDS)
        if (g < NR_) {
            float a0 = 0.f, a1 = 0.f;
            const float* bp = bt[g];
            #pragma unroll 4
            for (int j = lane; j < H_; j += 16) {
                a0 += bp[j] * hl[j];
                a1 += bp[j + 8] * hl[j + 8];
            }
            float a = a0 + a1;
            a += __shfl_xor(a, 1);
            a += __shfl_xor(a, 2);
            a += __shfl_xor(a, 4);
            if (lane == 0) u[g] = a;
        }
        __syncthreads();
        // v[g] = triangular combine
        if (g < NR_) {
            float a = 0.f;
            #pragma unroll
            for (int mi = 0; mi < 9; ++mi) {
                int m = mi * 8 + lane;
                a += (m < cnt) ? cfv[mi] * u[cnt - 1 - m] : 0.f;
            }
            a += __shfl_xor(a, 1);
            a += __shfl_xor(a, 2);
            a += __shfl_xor(a, 4);
            if (lane == 0) v[g] = a;
        }
        __syncthreads();
        float hv = 0.f;
        if (tid < H_) {
            float a0 = 0.f, a1 = 0.f;
            #pragma unroll
            for (int k = 0; k < NR_ - 1; k += 2) {
                a0 += bt[k][tid] * v[k];
                a1 += bt[k + 1][tid] * v[k + 1];
            }
            a0 += bt[NR_ - 1][tid] * v[NR_ - 1];
            hv = tanhf(yih[((size_t)t * B_ + b) * H_ + tid] + a0 + a1 + bv);
            out[((size_t)t * B_ + b) * H_ + tid] = hv;
        }
        __syncthreads();
        if (tid < H_) hl[tid] = hv;
        __syncthreads();
    }
}

extern "C" void kernel_launch(void* const* d_in, const int* in_sizes, int n_in,
                              void* d_out, int out_size, void* d_ws, size_t ws_size,
                              hipStream_t stream) {
    const float* x        = (const float*)d_in[0];
    const float* wih_ih   = (const float*)d_in[1];
    const float* wih_hh   = (const float*)d_in[2];
    const float* wih_b    = (const float*)d_in[3];
    const float* whh_ih   = (const float*)d_in[4];
    const float* whh_hh   = (const float*)d_in[5];
    const float* whh_b    = (const float*)d_in[6];
    const float* scal_ih  = (const float*)d_in[7];
    const float* scal_hh  = (const float*)d_in[8];
    const float* bias     = (const float*)d_in[9];
    const float* idct_in  = (const float*)d_in[10];
    const float* idct_hid = (const float*)d_in[11];
    float* out = (float*)d_out;

    char* ws = (char*)d_ws;
    size_t off = 0;
    auto alloc = [&](size_t bytes) -> void* {
        void* p = (void*)(ws + off);
        off += (bytes + 255) & ~(size_t)255;
        return p;
    };
    const size_t wt_bytes   = (size_t)2 * NC_ * G4_ * sizeof(ushort);
    const size_t rest_bytes = ((size_t)2 * T_ * B_ * G4_
                             + (size_t)2 * NS_ * B_ * G4_
                             + (size_t)2 * T_ * B_ * NC_
                             + (size_t)4 * B_ * NC_
                             + (size_t)T_ * B_ * H_
                             + (size_t)NR_ * H_) * sizeof(float) + 8192;
    bool useWT = (ws_size >= wt_bytes + rest_bytes);

    ushort* WT  = useWT ? (ushort*)alloc(wt_bytes) : nullptr;
    float* pre  = (float*)alloc((size_t)2 * T_ * B_ * G4_ * sizeof(float));
    float* part = (float*)alloc((size_t)2 * NS_ * B_ * G4_ * sizeof(float));
    float* hbuf = (float*)alloc((size_t)2 * T_ * B_ * NC_ * sizeof(float));
    float* hst  = (float*)alloc((size_t)2 * B_ * NC_ * sizeof(float));   // hst+cst adjacent
    float* cst  = (float*)alloc((size_t)2 * B_ * NC_ * sizeof(float));
    float* yih  = (float*)alloc((size_t)T_ * B_ * H_ * sizeof(float));
    float* Bt   = (float*)alloc((size_t)NR_ * H_ * sizeof(float));
    (void)cst;

    {   // hst and cst are contiguous (sizes are 256-byte multiples)
        int n = 4 * B_ * NC_;
        hipLaunchKernelGGL(k_zero, dim3((n + 255) / 256), dim3(256), 0, stream, hst, n);
    }
    if (useWT) {
        hipLaunchKernelGGL(k_transpose_bf16, dim3(80, 320, 2), dim3(32, 8), 0, stream,
                           wih_hh, whh_hh, (__hip_bfloat16*)WT);
    }
    hipLaunchKernelGGL(k_gih, dim3(4, 160, 2), dim3(256), 0, stream,
                       x, wih_ih, wih_b, whh_ih, whh_b, pre);
    hipLaunchKernelGGL(k_bt, dim3((NR_ * H_ + 255) / 256), dim3(256), 0, stream,
                       idct_hid, Bt);

    for (int t = 0; t < T_; ++t) {
        if (useWT) {
            hipLaunchKernelGGL(k_rec2, dim3(20, NS_, 2), dim3(256), 0, stream,
                               WT, hst, part);
        } else {
            hipLaunchKernelGGL((k_rec<false>), dim3(40, NS_, 2), dim3(256), 0, stream,
                               wih_hh, whh_hh, hst, part);
        }
        hipLaunchKernelGGL(k_gate, dim3((2 * B_ * NC_ + 255) / 256), dim3(256), 0, stream,
                           part, pre, scal_ih, scal_hh, cst, hst, hbuf, t);
    }

    hipLaunchKernelGGL(k_yih, dim3(T_ * B_), dim3(256), 0, stream,
                       x, idct_in, Bt, hbuf, yih);
    hipLaunchKernelGGL(k_seq, dim3(B_), dim3(576), 0, stream,
                       yih, Bt, hbuf + (size_t)T_ * B_ * NC_, bias, out);
}

// Round 4
// 1256.703 us; speedup vs baseline: 3.4218x; 1.6891x over previous
//
#include <hip/hip_runtime.h>
#include <hip/hip_bf16.h>

#define T_ 32
#define B_ 16
#define I_ 512
#define H_ 512
#define OFF_ 441
#define NR_ 71           // I_ - OFF_
#define NC_ 2556         // NR_*(NR_+1)/2
#define G4_ (4*NC_)      // 10224
#define NCP_ 2560        // NC_ padded to mult of 32 (and 640*4)
#define NT_ 639          // G4_/16 n-tiles
#define KC_ 640          // K-chunk (NCP_/NS_)
#define NS_ 4            // K-split for MFMA recurrent GEMM
#define NSF_ 8           // fallback K-split
#define KCHF_ 320        // fallback chunk

typedef __attribute__((ext_vector_type(8))) short bf16x8;
typedef __attribute__((ext_vector_type(4))) float f32x4;

__device__ __forceinline__ ushort bfc(float f) {
    __hip_bfloat16 h = __float2bfloat16(f);
    return *(ushort*)&h;
}
__device__ __forceinline__ float sigf(float x) { return 1.f / (1.f + expf(-x)); }

__global__ void k_zero(float* __restrict__ p, int n) {
    int i = blockIdx.x * 256 + threadIdx.x;
    if (i < n) p[i] = 0.f;
}

// x fp32 [512][512] -> bf16
__global__ void k_cvt_x(const float* __restrict__ x, ushort* __restrict__ xb) {
    int i = blockIdx.x * 256 + threadIdx.x;   // float4 slot, 65536 total
    float4 v = ((const float4*)x)[i];
    ushort4 o; o.x = bfc(v.x); o.y = bfc(v.y); o.z = bfc(v.z); o.w = bfc(v.w);
    ((ushort4*)xb)[i] = o;
}

// W[l] fp32 [G4][512] -> bf16 same layout
__global__ void k_cvt_w512(const float* __restrict__ W0, const float* __restrict__ W1,
                           ushort* __restrict__ dst) {
    int l = blockIdx.z;
    const float* src = l ? W1 : W0;
    size_t i = (size_t)blockIdx.x * 256 + threadIdx.x;   // float4 slot, G4*128 per layer
    float4 v = ((const float4*)src)[i];
    ushort4 o; o.x = bfc(v.x); o.y = bfc(v.y); o.z = bfc(v.z); o.w = bfc(v.w);
    ((ushort4*)(dst + (size_t)l * G4_ * I_))[i] = o;
}

// Whh[l] fp32 [G4][2556] -> bf16 [G4][2560] (pad 0)
__global__ void k_cvt_whh(const float* __restrict__ W0, const float* __restrict__ W1,
                          ushort* __restrict__ dst) {
    int l = blockIdx.z;
    const float* src = l ? W1 : W0;
    size_t idx = (size_t)blockIdx.x * 256 + threadIdx.x;  // slot over G4*640
    int r = (int)(idx / 640), s = (int)(idx - (size_t)r * 640);
    float4 v = make_float4(0.f, 0.f, 0.f, 0.f);
    if (s < 639) v = ((const float4*)(src + (size_t)r * NC_))[s];
    ushort4 o; o.x = bfc(v.x); o.y = bfc(v.y); o.z = bfc(v.z); o.w = bfc(v.w);
    ((ushort4*)(dst + ((size_t)l * G4_ + r) * NCP_))[s] = o;
}

// MFMA input GEMM: pre[l][m=t*B+b][n] = sum_k Xbf[m][k]*Wbf[l][n][k] + bias[n]
// block = 4 waves = 4 n-tiles; each wave does all 32 m-tiles; X staged frag-linear in LDS
__global__ __launch_bounds__(256) void k_gih_mfma(const ushort* __restrict__ Xbf,
        const ushort* __restrict__ Wbf,
        const float* __restrict__ b0, const float* __restrict__ b1,
        float* __restrict__ pre) {
    const int l = blockIdx.z;
    const float* bb = l ? b1 : b0;
    float* out = pre + (size_t)l * T_ * B_ * G4_;
    const int wid = threadIdx.x >> 6, lane = threadIdx.x & 63;
    int nt = blockIdx.x * 4 + wid;
    const bool act = nt < NT_;
    if (nt > NT_ - 1) nt = NT_ - 1;
    __shared__ ushort lds_a[32 * 64 * 8];   // 32 KB, frag-linear
    const int srow = lane & 15, skq = (lane >> 4) * 8;
    const ushort* wp = Wbf + (size_t)l * G4_ * I_ + (size_t)(nt * 16 + srow) * I_ + skq;
    f32x4 acc[32];
    #pragma unroll
    for (int mt = 0; mt < 32; ++mt) acc[mt] = (f32x4){0.f, 0.f, 0.f, 0.f};
    for (int ks = 0; ks < 16; ++ks) {
        #pragma unroll
        for (int i = 0; i < 8; ++i) {
            int mt = wid * 8 + i;
            bf16x8 xv = *(const bf16x8*)(Xbf + (size_t)(mt * 16 + srow) * I_ + ks * 32 + skq);
            *(bf16x8*)(lds_a + (mt * 64 + lane) * 8) = xv;
        }
        bf16x8 b = *(const bf16x8*)(wp + ks * 32);
        __syncthreads();
        #pragma unroll
        for (int mt = 0; mt < 32; ++mt) {
            bf16x8 a = *(const bf16x8*)(lds_a + (mt * 64 + lane) * 8);
            acc[mt] = __builtin_amdgcn_mfma_f32_16x16x32_bf16(a, b, acc[mt], 0, 0, 0);
        }
        __syncthreads();
    }
    if (act) {
        const int n = nt * 16 + srow;
        const float bv = bb[n];
        const int r0 = (lane >> 4) * 4;
        #pragma unroll
        for (int mt = 0; mt < 32; ++mt)
            #pragma unroll
            for (int v = 0; v < 4; ++v)
                out[(size_t)(mt * 16 + r0 + v) * G4_ + n] = acc[mt][v] + bv;
    }
}

// MFMA recurrent GEMM: part[l][s][b][j] = sum_{k in chunk s} hbf[l][b][k]*Wbf[l][j][k]
__global__ __launch_bounds__(256) void k_rec_mfma(const ushort* __restrict__ Wbf,
        const ushort* __restrict__ hbf, float* __restrict__ part) {
    const int l = blockIdx.z, s = blockIdx.y;
    const int wid = threadIdx.x >> 6, lane = threadIdx.x & 63;
    int nt = blockIdx.x * 4 + wid;
    const bool act = nt < NT_;
    if (nt > NT_ - 1) nt = NT_ - 1;
    const int j = nt * 16 + (lane & 15);
    const int kq = (lane >> 4) * 8;
    const ushort* wp = Wbf + ((size_t)l * G4_ + j) * NCP_ + s * KC_ + kq;
    const ushort* hp = hbf + ((size_t)l * B_ + (lane & 15)) * NCP_ + s * KC_ + kq;
    f32x4 acc = {0.f, 0.f, 0.f, 0.f};
    #pragma unroll 4
    for (int ks = 0; ks < KC_ / 32; ++ks) {
        bf16x8 a = *(const bf16x8*)(hp + ks * 32);
        bf16x8 b = *(const bf16x8*)(wp + ks * 32);
        acc = __builtin_amdgcn_mfma_f32_16x16x32_bf16(a, b, acc, 0, 0, 0);
    }
    if (act) {
        float* po = part + ((size_t)(l * NS_ + s) * B_) * G4_ + j;
        const int b0 = (lane >> 4) * 4;
        #pragma unroll
        for (int v = 0; v < 4; ++v)
            po[(size_t)(b0 + v) * G4_] = acc[v];
    }
}

// fp32 VALU input GEMM (fallback only)
__global__ __launch_bounds__(256) void k_gih(const float* __restrict__ X,
        const float* __restrict__ W0, const float* __restrict__ b0,
        const float* __restrict__ W1, const float* __restrict__ b1,
        float* __restrict__ pre) {
    const int l = blockIdx.z;
    const float* W = l ? W1 : W0;
    const float* bb = l ? b1 : b0;
    float* out = pre + (size_t)l * T_ * B_ * G4_;
    const int m0 = blockIdx.x * 128;
    const int n0 = blockIdx.y * 64;
    __shared__ float Xs[16][132];
    __shared__ float Ws[16][68];
    const int tid = threadIdx.x;
    const int tx = tid & 15, ty = tid >> 4;
    float acc[8][4] = {};
    for (int kt = 0; kt < I_; kt += 16) {
        #pragma unroll
        for (int i = 0; i < 2; ++i) {
            int idx = tid + i * 256;
            int kqq = idx >> 7, m = idx & 127;
            float4 xv = *(const float4*)&X[(size_t)(m0 + m) * I_ + kt + kqq * 4];
            Xs[kqq * 4 + 0][m] = xv.x; Xs[kqq * 4 + 1][m] = xv.y;
            Xs[kqq * 4 + 2][m] = xv.z; Xs[kqq * 4 + 3][m] = xv.w;
        }
        {
            int n = tid >> 2, kqq = tid & 3;
            float4 wv = make_float4(0.f, 0.f, 0.f, 0.f);
            if (n0 + n < G4_)
                wv = *(const float4*)&W[(size_t)(n0 + n) * I_ + kt + kqq * 4];
            Ws[kqq * 4 + 0][n] = wv.x; Ws[kqq * 4 + 1][n] = wv.y;
            Ws[kqq * 4 + 2][n] = wv.z; Ws[kqq * 4 + 3][n] = wv.w;
        }
        __syncthreads();
        #pragma unroll
        for (int kk = 0; kk < 16; ++kk) {
            float a[8], bv[4];
            #pragma unroll
            for (int p = 0; p < 8; ++p) a[p] = Xs[kk][ty * 8 + p];
            #pragma unroll
            for (int q = 0; q < 4; ++q) bv[q] = Ws[kk][tx * 4 + q];
            #pragma unroll
            for (int p = 0; p < 8; ++p)
                #pragma unroll
                for (int q = 0; q < 4; ++q) acc[p][q] += a[p] * bv[q];
        }
        __syncthreads();
    }
    #pragma unroll
    for (int p = 0; p < 8; ++p) {
        int m = m0 + ty * 8 + p;
        #pragma unroll
        for (int q = 0; q < 4; ++q) {
            int n = n0 + tx * 4 + q;
            if (n < G4_) out[(size_t)m * G4_ + n] = acc[p][q] + bb[n];
        }
    }
}

// fp32 strided fallback recurrent GEMM
__global__ __launch_bounds__(256) void k_rec_f(const float* __restrict__ Wt0,
        const float* __restrict__ Wt1,
        const float* __restrict__ hst, float* __restrict__ part) {
    int j = blockIdx.x * 256 + threadIdx.x;
    int s = blockIdx.y, l = blockIdx.z;
    if (j >= G4_) return;
    const float* wmat = l ? Wt1 : Wt0;
    const float* h = hst + (size_t)l * B_ * NC_;
    int k0 = s * KCHF_, k1 = (NC_ < k0 + KCHF_) ? NC_ : (k0 + KCHF_);
    float acc[B_] = {};
    #pragma unroll 4
    for (int k = k0; k < k1; ++k) {
        float w = wmat[(size_t)j * NC_ + k];
        #pragma unroll
        for (int b = 0; b < B_; ++b) acc[b] += h[b * NC_ + k] * w;
    }
    float* po = part + ((size_t)(l * NSF_ + s) * B_) * G4_ + j;
    #pragma unroll
    for (int b = 0; b < B_; ++b) po[(size_t)b * G4_] = acc[b];
}

// reduce K-split partials + pre, gates, update c,h; write bf16 h + scaled h
template <int NSP>
__global__ void k_gate(const float* __restrict__ part, const float* __restrict__ pre,
                       const float* __restrict__ scal_ih, const float* __restrict__ scal_hh,
                       float* __restrict__ cst, float* __restrict__ hst,
                       ushort* __restrict__ hbf, float* __restrict__ hbuf, int t) {
    int idx = blockIdx.x * 256 + threadIdx.x;
    if (idx >= 2 * B_ * NC_) return;
    int l = idx / (B_ * NC_);
    int r = idx - l * (B_ * NC_);
    int b = r / NC_;
    int jc = r - b * NC_;
    float g[4];
    #pragma unroll
    for (int q = 0; q < 4; ++q) {
        float s = pre[(((size_t)l * T_ + t) * B_ + b) * G4_ + q * NC_ + jc];
        #pragma unroll
        for (int sp = 0; sp < NSP; ++sp)
            s += part[((size_t)(l * NSP + sp) * B_ + b) * G4_ + q * NC_ + jc];
        g[q] = s;
    }
    float ci = cst[idx];
    float cn = sigf(g[1]) * ci + sigf(g[0]) * tanhf(g[2]);
    float hn = sigf(g[3]) * tanhf(cn);
    cst[idx] = cn;
    hst[idx] = hn;
    hbf[((size_t)l * B_ + b) * NCP_ + jc] = bfc(hn);
    float sc = (l ? scal_hh : scal_ih)[jc];
    hbuf[(((size_t)l * T_ + t) * B_ + b) * NC_ + jc] = hn * sc;
}

// Bt[k][h] = idct_hid[h][k] for k < 71
__global__ void k_bt(const float* __restrict__ Bh, float* __restrict__ Bt) {
    int idx = blockIdx.x * 256 + threadIdx.x;
    if (idx < NR_ * H_) {
        int k = idx / H_, h = idx - k * H_;
        Bt[idx] = Bh[(size_t)h * H_ + k];
    }
}

// yih[t,b,h] = sum_k Bt[k,h] * v[k]; coeffs pre-scaled in hbuf
__global__ __launch_bounds__(256) void k_yih(const float* __restrict__ x,
        const float* __restrict__ Ain, const float* __restrict__ Bt,
        const float* __restrict__ hbuf0, float* __restrict__ yih) {
    __shared__ float xl[I_];
    __shared__ float u[NR_];
    __shared__ float v[NR_];
    int tb = blockIdx.x;
    int tid = threadIdx.x;
    xl[tid] = x[(size_t)tb * I_ + tid];
    xl[tid + 256] = x[(size_t)tb * I_ + tid + 256];
    __syncthreads();
    if (tid < NR_) {
        float a = 0.f;
        for (int jj = 0; jj < I_; ++jj) a += Ain[(size_t)jj * I_ + tid] * xl[jj];
        u[tid] = a;
    }
    __syncthreads();
    if (tid < NR_) {
        int k = tid;
        int start = k * NR_ - (k * (k - 1)) / 2;
        int cnt = NR_ - k;
        const float* cf = hbuf0 + (size_t)tb * NC_;
        float a = 0.f;
        for (int m = 0; m < cnt; ++m) a += cf[start + m] * u[cnt - 1 - m];
        v[k] = a;
    }
    __syncthreads();
    for (int h = tid; h < H_; h += 256) {
        float a = 0.f;
        #pragma unroll
        for (int k = 0; k < NR_; ++k) a += Bt[(size_t)k * H_ + h] * v[k];
        yih[(size_t)tb * H_ + h] = a;
    }
}

// sequential phase-2; one block per batch; Bt in LDS (padded pitch 520, aligned b128)
#define BTP_ 520
__global__ __launch_bounds__(576) void k_seq(const float* __restrict__ yih,
        const float* __restrict__ Bt, const float* __restrict__ cf_all,
        const float* __restrict__ bias, float* __restrict__ out) {
    __shared__ __align__(16) float bt[NR_ * BTP_];   // 147.7 KB
    __shared__ __align__(16) float hl[H_];
    __shared__ float u[NR_ + 1];
    __shared__ __align__(16) float v[NR_ + 1];
    const int b = blockIdx.x, tid = threadIdx.x;
    for (int i = tid; i < NR_ * H_; i += 576)
        bt[(i >> 9) * BTP_ + (i & 511)] = Bt[i];
    for (int i = tid; i < H_; i += 576) hl[i] = 0.f;
    if (tid == 0) { u[NR_] = 0.f; v[NR_] = 0.f; }
    const float bv = (tid < H_) ? bias[tid] : 0.f;
    const int g = tid >> 3, lane = tid & 7;
    int start = 0, cnt = 0;
    if (g < NR_) { start = g * NR_ - (g * (g - 1)) / 2; cnt = NR_ - g; }
    __syncthreads();
    for (int t = 0; t < T_; ++t) {
        float cfv[9];
        if (g < NR_) {
            const float* cf = cf_all + ((size_t)t * B_ + b) * NC_ + start;
            #pragma unroll
            for (int mi = 0; mi < 9; ++mi) {
                int m = mi * 8 + lane;
                cfv[mi] = cf[m < cnt ? m : (cnt - 1)];
            }
        }
        // u[g] = sum_j bt[g][j]*h[j] via aligned float4 LDS reads
        if (g < NR_) {
            const float* bp = bt + g * BTP_ + lane * 4;
            const float* hp = hl + lane * 4;
            float a = 0.f;
            #pragma unroll
            for (int m = 0; m < 16; ++m) {
                float4 bq = *(const float4*)(bp + m * 32);
                float4 hq = *(const float4*)(hp + m * 32);
                a += bq.x * hq.x + bq.y * hq.y + bq.z * hq.z + bq.w * hq.w;
            }
            a += __shfl_xor(a, 1); a += __shfl_xor(a, 2); a += __shfl_xor(a, 4);
            if (lane == 0) u[g] = a;
        }
        __syncthreads();
        if (g < NR_) {
            float a = 0.f;
            #pragma unroll
            for (int mi = 0; mi < 9; ++mi) {
                int m = mi * 8 + lane;
                a += (m < cnt) ? cfv[mi] * u[cnt - 1 - m] : 0.f;
            }
            a += __shfl_xor(a, 1); a += __shfl_xor(a, 2); a += __shfl_xor(a, 4);
            if (lane == 0) v[g] = a;
        }
        __syncthreads();
        float hv = 0.f;
        if (tid < H_) {
            float4 vv[18];
            #pragma unroll
            for (int q = 0; q < 18; ++q) vv[q] = *(const float4*)(v + q * 4);
            float a0 = 0.f, a1 = 0.f;
            #pragma unroll
            for (int k = 0; k < NR_; ++k) {
                float vk = ((const float*)vv)[k];
                ((k & 1) ? a1 : a0) += bt[k * BTP_ + tid] * vk;
            }
            hv = tanhf(yih[((size_t)t * B_ + b) * H_ + tid] + a0 + a1 + bv);
            out[((size_t)t * B_ + b) * H_ + tid] = hv;
        }
        __syncthreads();
        if (tid < H_) hl[tid] = hv;
        __syncthreads();
    }
}

extern "C" void kernel_launch(void* const* d_in, const int* in_sizes, int n_in,
                              void* d_out, int out_size, void* d_ws, size_t ws_size,
                              hipStream_t stream) {
    const float* x        = (const float*)d_in[0];
    const float* wih_ih   = (const float*)d_in[1];
    const float* wih_hh   = (const float*)d_in[2];
    const float* wih_b    = (const float*)d_in[3];
    const float* whh_ih   = (const float*)d_in[4];
    const float* whh_hh   = (const float*)d_in[5];
    const float* whh_b    = (const float*)d_in[6];
    const float* scal_ih  = (const float*)d_in[7];
    const float* scal_hh  = (const float*)d_in[8];
    const float* bias     = (const float*)d_in[9];
    const float* idct_in  = (const float*)d_in[10];
    const float* idct_hid = (const float*)d_in[11];
    float* out = (float*)d_out;

    const size_t REG_B   = (size_t)2 * G4_ * NCP_ * 2;       // 104,693,760
    const size_t PRE_B   = (size_t)2 * T_ * B_ * G4_ * 4;    // 41,877,504
    const size_t PARTA_B = (size_t)2 * NS_  * B_ * G4_ * 4;  //  5,234,688
    const size_t PARTF_B = (size_t)2 * NSF_ * B_ * G4_ * 4;  // 10,469,376
    const size_t HBUF_B  = (size_t)2 * T_ * B_ * NC_ * 4;    // 10,469,376
    const size_t HBF_B   = (size_t)2 * B_ * NCP_ * 2;        //    163,840
    const size_t HST_B   = (size_t)2 * B_ * NC_ * 4;         //    327,168
    const size_t need_mfma = REG_B + PRE_B + PARTA_B + HBUF_B + HBF_B + 2 * HST_B;
    bool useWT = (ws_size >= need_mfma);

    char* ws = (char*)d_ws;
    size_t off = 0;
    auto alloc = [&](size_t bytes) -> void* {
        void* p = (void*)(ws + off);
        off += (bytes + 255) & ~(size_t)255;
        return p;
    };
    ushort* Wbf = nullptr; ushort* Wbf_ih = nullptr; ushort* Xbf = nullptr;
    if (useWT) {
        Wbf = (ushort*)alloc(REG_B);
        Wbf_ih = Wbf;                                  // alias: dead before cvt_whh
        Xbf = (ushort*)((char*)Wbf + 21000192);        // alias within region
    }
    float* pre  = (float*)alloc(PRE_B);
    float* part = (float*)alloc(useWT ? PARTA_B : PARTF_B);
    float* hbuf = (float*)alloc(HBUF_B);
    ushort* hbf = (ushort*)alloc(HBF_B);
    float* hst  = (float*)alloc(HST_B);
    float* cst  = (float*)alloc(HST_B);
    float* yih  = part;                                 // alias: part dead after loop
    float* Bt   = (float*)((char*)part + 1048576);

    {   // zero hbf + hst + cst (contiguous allocs)
        int n = (int)((HBF_B + 2 * HST_B) / 4);
        hipLaunchKernelGGL(k_zero, dim3((n + 255) / 256), dim3(256), 0, stream,
                           (float*)hbf, n);
    }

    if (useWT) {
        hipLaunchKernelGGL(k_cvt_x, dim3(256), dim3(256), 0, stream, x, Xbf);
        hipLaunchKernelGGL(k_cvt_w512, dim3(G4_ * 128 / 256, 1, 2), dim3(256), 0, stream,
                           wih_ih, whh_ih, Wbf_ih);
        hipLaunchKernelGGL(k_gih_mfma, dim3(160, 1, 2), dim3(256), 0, stream,
                           Xbf, Wbf_ih, wih_b, whh_b, pre);
        hipLaunchKernelGGL(k_cvt_whh, dim3(G4_ * 640 / 256, 1, 2), dim3(256), 0, stream,
                           wih_hh, whh_hh, Wbf);
        for (int t = 0; t < T_; ++t) {
            hipLaunchKernelGGL(k_rec_mfma, dim3(160, NS_, 2), dim3(256), 0, stream,
                               Wbf, hbf, part);
            hipLaunchKernelGGL((k_gate<NS_>), dim3(320), dim3(256), 0, stream,
                               part, pre, scal_ih, scal_hh, cst, hst, hbf, hbuf, t);
        }
    } else {
        hipLaunchKernelGGL(k_gih, dim3(4, 160, 2), dim3(256), 0, stream,
                           x, wih_ih, wih_b, whh_ih, whh_b, pre);
        for (int t = 0; t < T_; ++t) {
            hipLaunchKernelGGL(k_rec_f, dim3(40, NSF_, 2), dim3(256), 0, stream,
                               wih_hh, whh_hh, hst, part);
            hipLaunchKernelGGL((k_gate<NSF_>), dim3(320), dim3(256), 0, stream,
                               part, pre, scal_ih, scal_hh, cst, hst, hbf, hbuf, t);
        }
    }

    hipLaunchKernelGGL(k_bt, dim3((NR_ * H_ + 255) / 256), dim3(256), 0, stream,
                       idct_hid, Bt);
    hipLaunchKernelGGL(k_yih, dim3(T_ * B_), dim3(256), 0, stream,
                       x, idct_in, Bt, hbuf, yih);
    hipLaunchKernelGGL(k_seq, dim3(B_), dim3(576), 0, stream,
                       yih, Bt, hbuf + (size_t)T_ * B_ * NC_, bias, out);
}

// Round 5
// 1188.108 us; speedup vs baseline: 3.6193x; 1.0577x over previous
//
#include <hip/hip_runtime.h>
#include <hip/hip_bf16.h>

#define T_ 32
#define B_ 16
#define I_ 512
#define H_ 512
#define OFF_ 441
#define NR_ 71           // I_ - OFF_
#define NC_ 2556         // NR_*(NR_+1)/2
#define G4_ (4*NC_)      // 10224
#define NCP_ 2560        // K padded
#define NPR_ 10240       // padded gate-permuted row count
#define NTIL_ 640        // NPR_/16
#define NSF_ 8           // fallback K-split
#define KCHF_ 320        // fallback chunk

typedef __attribute__((ext_vector_type(8))) short bf16x8;
typedef __attribute__((ext_vector_type(4))) float f32x4;

__device__ __forceinline__ ushort bfc(float f) {
    __hip_bfloat16 h = __float2bfloat16(f);
    return *(ushort*)&h;
}
__device__ __forceinline__ float b2f(ushort u) {
    return __uint_as_float((uint)u << 16);
}
__device__ __forceinline__ float sigf(float x) { return 1.f / (1.f + expf(-x)); }

__global__ void k_zero(float* __restrict__ p, int n) {
    int i = blockIdx.x * 256 + threadIdx.x;
    if (i < n) p[i] = 0.f;
}

// x fp32 [512][512] -> bf16 same layout
__global__ void k_cvt_x(const float* __restrict__ x, ushort* __restrict__ xb) {
    int i = blockIdx.x * 256 + threadIdx.x;   // float4 slot, 65536 total
    float4 v = ((const float4*)x)[i];
    ushort4 o; o.x = bfc(v.x); o.y = bfc(v.y); o.z = bfc(v.z); o.w = bfc(v.w);
    ((ushort4*)xb)[i] = o;
}

// Wih[l] fp32 [G4][512] -> bf16 gate-permuted [NPR][512]; row n' = 4*jc+q <- q*NC+jc
__global__ void k_cvt_w512p(const float* __restrict__ W0, const float* __restrict__ W1,
                            ushort* __restrict__ dst) {
    int l = blockIdx.z;
    const float* src = l ? W1 : W0;
    size_t idx = (size_t)blockIdx.x * 256 + threadIdx.x;   // over NPR*128
    int np = (int)(idx >> 7), kq = (int)(idx & 127);
    ushort4 o; o.x = 0; o.y = 0; o.z = 0; o.w = 0;
    int jc = np >> 2, q = np & 3;
    if (jc < NC_) {
        float4 v = *(const float4*)(src + ((size_t)q * NC_ + jc) * I_ + kq * 4);
        o.x = bfc(v.x); o.y = bfc(v.y); o.z = bfc(v.z); o.w = bfc(v.w);
    }
    ((ushort4*)(dst + ((size_t)l * NPR_ + np) * I_))[kq] = o;
}

// Whh[l] fp32 [G4][2556] -> bf16 gate-permuted K-padded [NPR][2560]
__global__ void k_cvt_whhp(const float* __restrict__ W0, const float* __restrict__ W1,
                           ushort* __restrict__ dst) {
    int l = blockIdx.z;
    const float* src = l ? W1 : W0;
    size_t idx = (size_t)blockIdx.x * 256 + threadIdx.x;   // over NPR*640
    int np = (int)(idx / 640), s = (int)(idx - (size_t)np * 640);
    ushort4 o; o.x = 0; o.y = 0; o.z = 0; o.w = 0;
    int jc = np >> 2, q = np & 3;
    if (jc < NC_ && s < 639) {
        float4 v = *(const float4*)(src + ((size_t)q * NC_ + jc) * NC_ + s * 4);
        o.x = bfc(v.x); o.y = bfc(v.y); o.z = bfc(v.z); o.w = bfc(v.w);
    }
    ((ushort4*)(dst + ((size_t)l * NPR_ + np) * NCP_))[s] = o;
}

// MFMA input GEMM -> preT[l][n'][m] bf16, m = t*16+b; permuted bias added
__global__ __launch_bounds__(256) void k_gih_mfma(const ushort* __restrict__ Xbf,
        const ushort* __restrict__ Wp,
        const float* __restrict__ b0, const float* __restrict__ b1,
        ushort* __restrict__ preT) {
    const int l = blockIdx.z;
    const float* bb = l ? b1 : b0;
    const int wid = threadIdx.x >> 6, lane = threadIdx.x & 63;
    const int nt = blockIdx.x * 4 + wid;
    __shared__ ushort lds_a[32 * 64 * 8];   // 32 KB, frag-linear
    const int srow = lane & 15, skq = (lane >> 4) * 8;
    const ushort* wp = Wp + ((size_t)l * NPR_ + nt * 16 + srow) * I_ + skq;
    f32x4 acc[32];
    #pragma unroll
    for (int mt = 0; mt < 32; ++mt) acc[mt] = (f32x4){0.f, 0.f, 0.f, 0.f};
    for (int ks = 0; ks < 16; ++ks) {
        #pragma unroll
        for (int i = 0; i < 8; ++i) {
            int mt = wid * 8 + i;
            bf16x8 xv = *(const bf16x8*)(Xbf + (size_t)(mt * 16 + srow) * I_ + ks * 32 + skq);
            *(bf16x8*)(lds_a + (mt * 64 + lane) * 8) = xv;
        }
        bf16x8 b = *(const bf16x8*)(wp + ks * 32);
        __syncthreads();
        #pragma unroll
        for (int mt = 0; mt < 32; ++mt) {
            bf16x8 a = *(const bf16x8*)(lds_a + (mt * 64 + lane) * 8);
            acc[mt] = __builtin_amdgcn_mfma_f32_16x16x32_bf16(a, b, acc[mt], 0, 0, 0);
        }
        __syncthreads();
    }
    const int n = nt * 16 + srow;
    const float bv = (n < G4_) ? bb[(size_t)(n & 3) * NC_ + (n >> 2)] : 0.f;
    const int r0 = (lane >> 4) * 4;
    ushort* po = preT + ((size_t)l * NPR_ + n) * 512;
    #pragma unroll
    for (int mt = 0; mt < 32; ++mt) {
        ushort4 o;
        o.x = bfc(acc[mt][0] + bv); o.y = bfc(acc[mt][1] + bv);
        o.z = bfc(acc[mt][2] + bv); o.w = bfc(acc[mt][3] + bv);
        *(ushort4*)(po + mt * 16 + r0) = o;
    }
}

// Fused recurrent step: GEMM(h@Whh') + pre -> gates -> c,h update. 1 wave/block.
__global__ __launch_bounds__(64) void k_step(const ushort* __restrict__ Wp,
        const ushort* __restrict__ preT,
        const ushort* __restrict__ hbf_in, ushort* __restrict__ hbf_out,
        float* __restrict__ cst, float* __restrict__ hbuf,
        const float* __restrict__ scal_ih, const float* __restrict__ scal_hh,
        int t) {
    const int l = blockIdx.z;
    const int nt = blockIdx.x;
    const int lane = threadIdx.x;
    const int col = lane & 15;          // n'-local / also batch for gate pass
    const int kq = (lane >> 4) * 8;
    const ushort* wp = Wp + ((size_t)l * NPR_ + nt * 16 + col) * NCP_ + kq;
    const ushort* hp = hbf_in + ((size_t)l * B_ + col) * NCP_ + kq;
    f32x4 acc = {0.f, 0.f, 0.f, 0.f};
    #pragma unroll 8
    for (int ks = 0; ks < NCP_ / 32; ++ks) {
        bf16x8 a = *(const bf16x8*)(hp + ks * 32);
        bf16x8 b = *(const bf16x8*)(wp + ks * 32);
        acc = __builtin_amdgcn_mfma_f32_16x16x32_bf16(a, b, acc, 0, 0, 0);
    }
    __shared__ float gl[16][17];
    const int m0 = (lane >> 4) * 4;
    {
        const ushort4 p4 = *(const ushort4*)(preT +
            ((size_t)l * NPR_ + nt * 16 + col) * 512 + t * 16 + m0);
        gl[col][m0 + 0] = acc[0] + b2f(p4.x);
        gl[col][m0 + 1] = acc[1] + b2f(p4.y);
        gl[col][m0 + 2] = acc[2] + b2f(p4.z);
        gl[col][m0 + 3] = acc[3] + b2f(p4.w);
    }
    __syncthreads();
    // gate pass: lane -> (b = col, jq = lane>>4), jc = nt*4+jq
    const int jq = lane >> 4;
    const int jc = nt * 4 + jq;
    if (jc < NC_) {
        const int b = col;
        float g0 = gl[jq * 4 + 0][b];
        float g1 = gl[jq * 4 + 1][b];
        float g2 = gl[jq * 4 + 2][b];
        float g3 = gl[jq * 4 + 3][b];
        float* cp = cst + ((size_t)l * NC_ + jc) * B_ + b;
        float ci = *cp;
        float cn = sigf(g1) * ci + sigf(g0) * tanhf(g2);
        float hn = sigf(g3) * tanhf(cn);
        *cp = cn;
        hbf_out[((size_t)l * B_ + b) * NCP_ + jc] = bfc(hn);
        float sc = (l ? scal_hh : scal_ih)[jc];
        hbuf[(((size_t)l * T_ + t) * B_ + b) * NC_ + jc] = hn * sc;
    }
}

// ---------------- fallback path (small workspace) ----------------
__global__ __launch_bounds__(256) void k_gih(const float* __restrict__ X,
        const float* __restrict__ W0, const float* __restrict__ b0,
        const float* __restrict__ W1, const float* __restrict__ b1,
        float* __restrict__ pre) {
    const int l = blockIdx.z;
    const float* W = l ? W1 : W0;
    const float* bb = l ? b1 : b0;
    float* out = pre + (size_t)l * T_ * B_ * G4_;
    const int m0 = blockIdx.x * 128;
    const int n0 = blockIdx.y * 64;
    __shared__ float Xs[16][132];
    __shared__ float Ws[16][68];
    const int tid = threadIdx.x;
    const int tx = tid & 15, ty = tid >> 4;
    float acc[8][4] = {};
    for (int kt = 0; kt < I_; kt += 16) {
        #pragma unroll
        for (int i = 0; i < 2; ++i) {
            int idx = tid + i * 256;
            int kqq = idx >> 7, m = idx & 127;
            float4 xv = *(const float4*)&X[(size_t)(m0 + m) * I_ + kt + kqq * 4];
            Xs[kqq * 4 + 0][m] = xv.x; Xs[kqq * 4 + 1][m] = xv.y;
            Xs[kqq * 4 + 2][m] = xv.z; Xs[kqq * 4 + 3][m] = xv.w;
        }
        {
            int n = tid >> 2, kqq = tid & 3;
            float4 wv = make_float4(0.f, 0.f, 0.f, 0.f);
            if (n0 + n < G4_)
                wv = *(const float4*)&W[(size_t)(n0 + n) * I_ + kt + kqq * 4];
            Ws[kqq * 4 + 0][n] = wv.x; Ws[kqq * 4 + 1][n] = wv.y;
            Ws[kqq * 4 + 2][n] = wv.z; Ws[kqq * 4 + 3][n] = wv.w;
        }
        __syncthreads();
        #pragma unroll
        for (int kk = 0; kk < 16; ++kk) {
            float a[8], bv[4];
            #pragma unroll
            for (int p = 0; p < 8; ++p) a[p] = Xs[kk][ty * 8 + p];
            #pragma unroll
            for (int q = 0; q < 4; ++q) bv[q] = Ws[kk][tx * 4 + q];
            #pragma unroll
            for (int p = 0; p < 8; ++p)
                #pragma unroll
                for (int q = 0; q < 4; ++q) acc[p][q] += a[p] * bv[q];
        }
        __syncthreads();
    }
    #pragma unroll
    for (int p = 0; p < 8; ++p) {
        int m = m0 + ty * 8 + p;
        #pragma unroll
        for (int q = 0; q < 4; ++q) {
            int n = n0 + tx * 4 + q;
            if (n < G4_) out[(size_t)m * G4_ + n] = acc[p][q] + bb[n];
        }
    }
}

__global__ __launch_bounds__(256) void k_rec_f(const float* __restrict__ Wt0,
        const float* __restrict__ Wt1,
        const float* __restrict__ hst, float* __restrict__ part) {
    int j = blockIdx.x * 256 + threadIdx.x;
    int s = blockIdx.y, l = blockIdx.z;
    if (j >= G4_) return;
    const float* wmat = l ? Wt1 : Wt0;
    const float* h = hst + (size_t)l * B_ * NC_;
    int k0 = s * KCHF_, k1 = (NC_ < k0 + KCHF_) ? NC_ : (k0 + KCHF_);
    float acc[B_] = {};
    #pragma unroll 4
    for (int k = k0; k < k1; ++k) {
        float w = wmat[(size_t)j * NC_ + k];
        #pragma unroll
        for (int b = 0; b < B_; ++b) acc[b] += h[b * NC_ + k] * w;
    }
    float* po = part + ((size_t)(l * NSF_ + s) * B_) * G4_ + j;
    #pragma unroll
    for (int b = 0; b < B_; ++b) po[(size_t)b * G4_] = acc[b];
}

__global__ void k_gate_f(const float* __restrict__ part, const float* __restrict__ pre,
                         const float* __restrict__ scal_ih, const float* __restrict__ scal_hh,
                         float* __restrict__ cst, float* __restrict__ hst,
                         float* __restrict__ hbuf, int t) {
    int idx = blockIdx.x * 256 + threadIdx.x;
    if (idx >= 2 * B_ * NC_) return;
    int l = idx / (B_ * NC_);
    int r = idx - l * (B_ * NC_);
    int b = r / NC_;
    int jc = r - b * NC_;
    float g[4];
    #pragma unroll
    for (int q = 0; q < 4; ++q) {
        float s = pre[(((size_t)l * T_ + t) * B_ + b) * G4_ + q * NC_ + jc];
        #pragma unroll
        for (int sp = 0; sp < NSF_; ++sp)
            s += part[((size_t)(l * NSF_ + sp) * B_ + b) * G4_ + q * NC_ + jc];
        g[q] = s;
    }
    float ci = cst[idx];
    float cn = sigf(g[1]) * ci + sigf(g[0]) * tanhf(g[2]);
    float hn = sigf(g[3]) * tanhf(cn);
    cst[idx] = cn;
    hst[idx] = hn;
    float sc = (l ? scal_hh : scal_ih)[jc];
    hbuf[(((size_t)l * T_ + t) * B_ + b) * NC_ + jc] = hn * sc;
}
// ---------------- end fallback ----------------

// Bt[k][h] = idct_hid[h][k] for k < 71
__global__ void k_bt(const float* __restrict__ Bh, float* __restrict__ Bt) {
    int idx = blockIdx.x * 256 + threadIdx.x;
    if (idx < NR_ * H_) {
        int k = idx / H_, h = idx - k * H_;
        Bt[idx] = Bh[(size_t)h * H_ + k];
    }
}

// yih[t,b,h] = sum_k Bt[k,h] * v[k]; coeffs pre-scaled in hbuf
__global__ __launch_bounds__(256) void k_yih(const float* __restrict__ x,
        const float* __restrict__ Ain, const float* __restrict__ Bt,
        const float* __restrict__ hbuf0, float* __restrict__ yih) {
    __shared__ float xl[I_];
    __shared__ float u[NR_];
    __shared__ float v[NR_];
    int tb = blockIdx.x;
    int tid = threadIdx.x;
    xl[tid] = x[(size_t)tb * I_ + tid];
    xl[tid + 256] = x[(size_t)tb * I_ + tid + 256];
    __syncthreads();
    if (tid < NR_) {
        float a = 0.f;
        for (int jj = 0; jj < I_; ++jj) a += Ain[(size_t)jj * I_ + tid] * xl[jj];
        u[tid] = a;
    }
    __syncthreads();
    if (tid < NR_) {
        int k = tid;
        int start = k * NR_ - (k * (k - 1)) / 2;
        int cnt = NR_ - k;
        const float* cf = hbuf0 + (size_t)tb * NC_;
        float a = 0.f;
        for (int m = 0; m < cnt; ++m) a += cf[start + m] * u[cnt - 1 - m];
        v[k] = a;
    }
    __syncthreads();
    for (int h = tid; h < H_; h += 256) {
        float a = 0.f;
        #pragma unroll
        for (int k = 0; k < NR_; ++k) a += Bt[(size_t)k * H_ + h] * v[k];
        yih[(size_t)tb * H_ + h] = a;
    }
}

// sequential phase-2; one block per batch; Bt in LDS (pitch 520, b128-aligned)
#define BTP_ 520
__global__ __launch_bounds__(576) void k_seq(const float* __restrict__ yih,
        const float* __restrict__ Bt, const float* __restrict__ cf_all,
        const float* __restrict__ bias, float* __restrict__ out) {
    __shared__ __align__(16) float bt[NR_ * BTP_];   // 147.7 KB
    __shared__ __align__(16) float hl[H_];
    __shared__ float u[NR_ + 1];
    __shared__ __align__(16) float v[NR_ + 1];
    const int b = blockIdx.x, tid = threadIdx.x;
    for (int i = tid; i < NR_ * H_; i += 576)
        bt[(i >> 9) * BTP_ + (i & 511)] = Bt[i];
    for (int i = tid; i < H_; i += 576) hl[i] = 0.f;
    if (tid == 0) { u[NR_] = 0.f; v[NR_] = 0.f; }
    const float bv = (tid < H_) ? bias[tid] : 0.f;
    const int g = tid >> 3, lane = tid & 7;
    int start = 0, cnt = 0;
    if (g < NR_) { start = g * NR_ - (g * (g - 1)) / 2; cnt = NR_ - g; }
    __syncthreads();
    for (int t = 0; t < T_; ++t) {
        float cfv[9];
        if (g < NR_) {
            const float* cf = cf_all + ((size_t)t * B_ + b) * NC_ + start;
            #pragma unroll
            for (int mi = 0; mi < 9; ++mi) {
                int m = mi * 8 + lane;
                cfv[mi] = cf[m < cnt ? m : (cnt - 1)];
            }
        }
        if (g < NR_) {
            const float* bp = bt + g * BTP_ + lane * 4;
            const float* hp = hl + lane * 4;
            float a = 0.f;
            #pragma unroll
            for (int m = 0; m < 16; ++m) {
                float4 bq = *(const float4*)(bp + m * 32);
                float4 hq = *(const float4*)(hp + m * 32);
                a += bq.x * hq.x + bq.y * hq.y + bq.z * hq.z + bq.w * hq.w;
            }
            a += __shfl_xor(a, 1); a += __shfl_xor(a, 2); a += __shfl_xor(a, 4);
            if (lane == 0) u[g] = a;
        }
        __syncthreads();
        if (g < NR_) {
            float a = 0.f;
            #pragma unroll
            for (int mi = 0; mi < 9; ++mi) {
                int m = mi * 8 + lane;
                a += (m < cnt) ? cfv[mi] * u[cnt - 1 - m] : 0.f;
            }
            a += __shfl_xor(a, 1); a += __shfl_xor(a, 2); a += __shfl_xor(a, 4);
            if (lane == 0) v[g] = a;
        }
        __syncthreads();
        float hv = 0.f;
        if (tid < H_) {
            float4 vv[18];
            #pragma unroll
            for (int q = 0; q < 18; ++q) vv[q] = *(const float4*)(v + q * 4);
            float a0 = 0.f, a1 = 0.f;
            #pragma unroll
            for (int k = 0; k < NR_; ++k) {
                float vk = ((const float*)vv)[k];
                ((k & 1) ? a1 : a0) += bt[k * BTP_ + tid] * vk;
            }
            hv = tanhf(yih[((size_t)t * B_ + b) * H_ + tid] + a0 + a1 + bv);
            out[((size_t)t * B_ + b) * H_ + tid] = hv;
        }
        __syncthreads();
        if (tid < H_) hl[tid] = hv;
        __syncthreads();
    }
}

extern "C" void kernel_launch(void* const* d_in, const int* in_sizes, int n_in,
                              void* d_out, int out_size, void* d_ws, size_t ws_size,
                              hipStream_t stream) {
    const float* x        = (const float*)d_in[0];
    const float* wih_ih   = (const float*)d_in[1];
    const float* wih_hh   = (const float*)d_in[2];
    const float* wih_b    = (const float*)d_in[3];
    const float* whh_ih   = (const float*)d_in[4];
    const float* whh_hh   = (const float*)d_in[5];
    const float* whh_b    = (const float*)d_in[6];
    const float* scal_ih  = (const float*)d_in[7];
    const float* scal_hh  = (const float*)d_in[8];
    const float* bias     = (const float*)d_in[9];
    const float* idct_in  = (const float*)d_in[10];
    const float* idct_hid = (const float*)d_in[11];
    float* out = (float*)d_out;

    const size_t WP_B   = (size_t)2 * NPR_ * NCP_ * 2;    // 104,857,600
    const size_t PRET_B = (size_t)2 * NPR_ * 512 * 2;     //  20,971,520
    const size_t HBUF_B = (size_t)2 * T_ * B_ * NC_ * 4;  //  10,469,376
    const size_t HBF_B  = (size_t)2 * 2 * B_ * NCP_ * 2;  //     655,360 (ping-pong)
    const size_t CST_B  = (size_t)2 * NC_ * B_ * 4;       //     327,168
    const size_t YIH_B  = (size_t)T_ * B_ * H_ * 4;
    const size_t BT_B   = (size_t)NR_ * H_ * 4;
    const size_t need_mfma = WP_B + PRET_B + HBUF_B + HBF_B + CST_B + YIH_B + BT_B + 4096;

    char* ws = (char*)d_ws;
    size_t off = 0;
    auto alloc = [&](size_t bytes) -> void* {
        void* p = (void*)(ws + off);
        off += (bytes + 255) & ~(size_t)255;
        return p;
    };

    if (ws_size >= need_mfma) {
        ushort* Wp   = (ushort*)alloc(WP_B);
        ushort* preT = (ushort*)alloc(PRET_B);
        float*  hbuf = (float*)alloc(HBUF_B);
        ushort* hbf  = (ushort*)alloc(HBF_B);
        float*  cst  = (float*)alloc(CST_B);
        float*  yih  = (float*)alloc(YIH_B);
        float*  Bt   = (float*)alloc(BT_B);
        // aliases inside Wp region (dead before k_cvt_whhp runs)
        ushort* Wih_p = Wp;
        ushort* Xbf   = (ushort*)((char*)Wp + 21000192);

        {   // zero hbf (both buffers) + cst (contiguous allocs)
            int n = (int)((HBF_B + 256 + CST_B) / 4);
            hipLaunchKernelGGL(k_zero, dim3((n + 255) / 256), dim3(256), 0, stream,
                               (float*)hbf, n);
        }
        hipLaunchKernelGGL(k_cvt_x, dim3(256), dim3(256), 0, stream, x, Xbf);
        hipLaunchKernelGGL(k_cvt_w512p, dim3(NPR_ * 128 / 256, 1, 2), dim3(256), 0, stream,
                           wih_ih, whh_ih, Wih_p);
        hipLaunchKernelGGL(k_gih_mfma, dim3(160, 1, 2), dim3(256), 0, stream,
                           Xbf, Wih_p, wih_b, whh_b, preT);
        hipLaunchKernelGGL(k_cvt_whhp, dim3(NPR_ * 640 / 256, 1, 2), dim3(256), 0, stream,
                           wih_hh, whh_hh, Wp);

        const size_t HS = (size_t)2 * B_ * NCP_;   // ushorts per ping-pong buffer
        for (int t = 0; t < T_; ++t) {
            const ushort* hin  = hbf + (size_t)(t & 1) * HS;
            ushort*       hout = hbf + (size_t)((t & 1) ^ 1) * HS;
            hipLaunchKernelGGL(k_step, dim3(NTIL_, 1, 2), dim3(64), 0, stream,
                               Wp, preT, hin, hout, cst, hbuf, scal_ih, scal_hh, t);
        }

        hipLaunchKernelGGL(k_bt, dim3((NR_ * H_ + 255) / 256), dim3(256), 0, stream,
                           idct_hid, Bt);
        hipLaunchKernelGGL(k_yih, dim3(T_ * B_), dim3(256), 0, stream,
                           x, idct_in, Bt, hbuf, yih);
        hipLaunchKernelGGL(k_seq, dim3(B_), dim3(576), 0, stream,
                           yih, Bt, hbuf + (size_t)T_ * B_ * NC_, bias, out);
    } else {
        // fp32 fallback
        float* pre  = (float*)alloc((size_t)2 * T_ * B_ * G4_ * 4);
        float* part = (float*)alloc((size_t)2 * NSF_ * B_ * G4_ * 4);
        float* hbuf = (float*)alloc(HBUF_B);
        float* hst  = (float*)alloc((size_t)2 * B_ * NC_ * 4);
        float* cst  = (float*)alloc((size_t)2 * B_ * NC_ * 4);
        float* yih  = (float*)alloc(YIH_B);
        float* Bt   = (float*)alloc(BT_B);
        {
            int n = 4 * B_ * NC_;
            hipLaunchKernelGGL(k_zero, dim3((n + 255) / 256), dim3(256), 0, stream, hst, n);
        }
        hipLaunchKernelGGL(k_gih, dim3(4, 160, 2), dim3(256), 0, stream,
                           x, wih_ih, wih_b, whh_ih, whh_b, pre);
        for (int t = 0; t < T_; ++t) {
            hipLaunchKernelGGL(k_rec_f, dim3(40, NSF_, 2), dim3(256), 0, stream,
                               wih_hh, whh_hh, hst, part);
            hipLaunchKernelGGL(k_gate_f, dim3(320), dim3(256), 0, stream,
                               part, pre, scal_ih, scal_hh, cst, hst, hbuf, t);
        }
        hipLaunchKernelGGL(k_bt, dim3((NR_ * H_ + 255) / 256), dim3(256), 0, stream,
                           idct_hid, Bt);
        hipLaunchKernelGGL(k_yih, dim3(T_ * B_), dim3(256), 0, stream,
                           x, idct_in, Bt, hbuf, yih);
        hipLaunchKernelGGL(k_seq, dim3(B_), dim3(576), 0, stream,
                           yih, Bt, hbuf + (size_t)T_ * B_ * NC_, bias, out);
    }
}